// Round 1
// baseline (4321.061 us; speedup 1.0000x reference)
//
#include <hip/hip_runtime.h>
#include <cstdint>

#define WIN   32
#define NPIX  1024
#define NH    992
#define NEDGE 1984
#define NSORT 2048

__global__ __launch_bounds__(64) void malis_kernel(
    const float* __restrict__ pred,
    const float* __restrict__ target,
    const float* __restrict__ lr_p,
    const float* __restrict__ lrp_p,
    float* __restrict__ out)
{
    const int tid = threadIdx.x;
    const int bid = blockIdx.x;
    const int bb  = bid >> 6;        // batch
    const int win = bid & 63;
    const int wy  = win >> 3, wx = win & 7;
    const int base = bb * 65536 + (wy * 32) * 256 + wx * 32;

    // ---- LDS ----
    __shared__ unsigned long long keys[NSORT];     // 16384 B (overlaid early: masks+labId)
    __shared__ float predL[NPIX];                  // 4096
    __shared__ float costs[NEDGE];                 // 7936
    __shared__ float w[NEDGE];                     // 7936
    __shared__ short seg[NPIX];                    // 2048 (CCL labels -> compact seg)
    __shared__ short parent[NPIX], szN[NPIX], szL[NPIX];
    __shared__ short headL[NPIX], tailL[NPIX], nxt[NPIX];
    __shared__ short hist[NPIX + 1];               // 2050
    __shared__ unsigned short ea[NEDGE], eb[NEDGE];// 7936
    __shared__ unsigned char tgtL[NPIX];           // 1024
    __shared__ unsigned char gtcL[NEDGE];          // 1984
    __shared__ int flags[2];                       // [0]=changed flag, [1]=label counter

    // early-phase scratch overlaid on keys[] (dead until sort)
    unsigned char* mA    = (unsigned char*)keys;          // 1024 B
    unsigned char* mB    = mA + NPIX;                     // 1024 B
    short*         labId = (short*)(mA + 2 * NPIX);       // 2048 B

    // ---- load window ----
    for (int i = tid; i < NPIX; i += 64) {
        int r = i >> 5, c = i & 31;
        float pv = pred[base + r * 256 + c];
        float tv = target[base + r * 256 + c];
        predL[i] = pv;
        tgtL[i]  = (unsigned char)tv;        // exact small ints 0..25
        mA[i]    = (tv == 0.0f) ? 1 : 0;
    }
    if (tid == 0) flags[1] = 0;
    __syncthreads();

    // ---- dilate 5x, 4-neighborhood (matches reference _dilate) ----
    unsigned char* src = mA;
    unsigned char* dst = mB;
    for (int it = 0; it < 5; ++it) {
        for (int i = tid; i < NPIX; i += 64) {
            int r = i >> 5, c = i & 31;
            unsigned char v = src[i];
            if (r > 0)  v |= src[i - 32];
            if (r < 31) v |= src[i + 32];
            if (c > 0)  v |= src[i - 1];
            if (c < 31) v |= src[i + 1];
            dst[i] = v;
        }
        __syncthreads();
        unsigned char* t_ = src; src = dst; dst = t_;
    }

    // ---- CCL (8-conn) on fg = !dilated, min-index propagation + pointer jumps ----
    for (int i = tid; i < NPIX; i += 64)
        seg[i] = src[i] ? (short)-1 : (short)i;
    __syncthreads();

    for (;;) {
        if (tid == 0) flags[0] = 0;
        __syncthreads();
        bool any = false;
        for (int i = tid; i < NPIX; i += 64) {
            short cur = seg[i];
            if (cur < 0) continue;
            int r = i >> 5, c = i & 31;
            int m = cur;
            #pragma unroll
            for (int dy = -1; dy <= 1; ++dy)
                #pragma unroll
                for (int dx = -1; dx <= 1; ++dx) {
                    if (dy == 0 && dx == 0) continue;
                    int rr = r + dy, cc = c + dx;
                    if ((unsigned)rr < 32u && (unsigned)cc < 32u) {
                        short nv = seg[rr * 32 + cc];
                        if (nv >= 0 && nv < m) m = nv;
                    }
                }
            short j1 = seg[m]; if (j1 >= 0 && j1 < m) m = j1;
            short j2 = seg[m]; if (j2 >= 0 && j2 < m) m = j2;
            if (m < (int)cur) { seg[i] = (short)m; any = true; }
        }
        if (any) flags[0] = 1;
        __syncthreads();
        if (flags[0] == 0) break;
        __syncthreads();
    }

    // compact label ids: seg -> 0 (bg) or 1..K
    for (int i = tid; i < NPIX; i += 64)
        if (seg[i] == (short)i) labId[i] = (short)atomicAdd(&flags[1], 1);
    __syncthreads();
    for (int i = tid; i < NPIX; i += 64) {
        short s = seg[i];
        seg[i] = (s < 0) ? (short)0 : (short)(labId[s] + 1);
    }
    __syncthreads();

    // ---- edges: costs + gtc (reference edge ordering: 992 horizontal then 992 vertical) ----
    for (int e = tid; e < NEDGE; e += 64) {
        int a, b2;
        if (e < NH) { int r = e / 31, c = e - r * 31; a = r * 32 + c; b2 = a + 1; }
        else        { int q = e - NH; int r = q >> 5, c = q & 31; a = r * 32 + c; b2 = a + 32; }
        ea[e] = (unsigned short)a; eb[e] = (unsigned short)b2;
        costs[e] = predL[a] + predL[b2];
        gtcL[e]  = (unsigned char)(tgtL[a] + tgtL[b2]);
    }
    __syncthreads();

    const float lr  = lr_p[0];
    const float lrp = lrp_p[0];
    float lossAcc = 0.0f;

    for (int phase = 0; phase < 2; ++phase) {
        const bool pos = (phase == 1);

        // build sort keys: (~bits(cost) << 32) | e  => ascending sort == (cost desc, idx asc)
        for (int e = tid; e < NEDGE; e += 64) {
            float cv = costs[e];
            int g = gtcL[e];
            if (!pos) { if (g > 20) cv = 20.0f; }
            else      { if (g < 10) cv = 0.0f; }
            unsigned int bits = __float_as_uint(cv);   // costs >= 0: bit pattern is monotone
            keys[e] = (((unsigned long long)(~bits)) << 32) | (unsigned int)e;
        }
        for (int e = NEDGE + tid; e < NSORT; e += 64) keys[e] = ~0ULL;

        // init union-find + labeled-member lists
        for (int i = tid; i < NPIX; i += 64) {
            parent[i] = (short)i;
            szN[i] = 1;
            short s = seg[i];
            szL[i] = s ? 1 : 0;
            headL[i] = tailL[i] = s ? (short)i : (short)-1;
            nxt[i] = -1;
        }
        for (int i = tid; i <= NPIX; i += 64) hist[i] = 0;
        for (int e = tid; e < NEDGE; e += 64) w[e] = 0.0f;
        __syncthreads();

        // bitonic sort ascending, 2048 u64
        for (int k = 2; k <= NSORT; k <<= 1) {
            for (int j = k >> 1; j > 0; j >>= 1) {
                for (int i = tid; i < NSORT; i += 64) {
                    int ixj = i ^ j;
                    if (ixj > i) {
                        unsigned long long x = keys[i], y = keys[ixj];
                        bool up = ((i & k) == 0);
                        if ((x > y) == up) { keys[i] = y; keys[ixj] = x; }
                    }
                }
                __syncthreads();
            }
        }

        // serial Kruskal (lane 0) — exact reference merge order
        if (tid == 0) {
            for (int s = 0; s < NEDGE; ++s) {
                int e  = (int)(unsigned int)keys[s];
                int a  = ea[e], b2 = eb[e];
                int fa = a;
                while (parent[fa] != fa) { short g = parent[parent[fa]]; parent[fa] = g; fa = g; }
                int fb = b2;
                while (parent[fb] != fb) { short g = parent[parent[fb]]; parent[fb] = g; fb = g; }
                if (fa == fb) continue;
                int la = szL[fa], lb = szL[fb];
                if (la > 0 && lb > 0) {
                    int s1 = fa, s2 = fb;
                    if (la > lb) { s1 = fb; s2 = fa; }
                    for (int p = headL[s1]; p >= 0; p = nxt[p]) hist[seg[p]]++;
                    int same = 0;
                    for (int p = headL[s2]; p >= 0; p = nxt[p]) same += hist[seg[p]];
                    for (int p = headL[s1]; p >= 0; p = nxt[p]) hist[seg[p]] = 0;
                    w[e] = (float)(pos ? same : (la * lb - same));
                }
                // union by node size (direction irrelevant to weights)
                if (szN[fa] < szN[fb]) { int t_ = fa; fa = fb; fb = t_; }
                parent[fb] = (short)fa;
                szN[fa] = (short)(szN[fa] + szN[fb]);
                szL[fa] = (short)(la + lb);
                if (headL[fb] >= 0) {
                    if (headL[fa] < 0) { headL[fa] = headL[fb]; tailL[fa] = tailL[fb]; }
                    else { nxt[tailL[fa]] = headL[fb]; tailL[fa] = tailL[fb]; }
                }
            }
        }
        __syncthreads();

        // normalization sum (over ALL edges, pre-mask — matches reference)
        float s_loc = 0.0f;
        for (int e = tid; e < NEDGE; e += 64) s_loc += w[e];
        #pragma unroll
        for (int off = 32; off > 0; off >>= 1) s_loc += __shfl_xor(s_loc, off, 64);
        const float sn = s_loc;

        // masked, normalized per-edge loss:  sum_e w_e * (f(p_a) + f(p_b))
        for (int e = tid; e < NEDGE; e += 64) {
            float wv = w[e];
            if (wv == 0.0f) continue;
            if (sn > 0.0f) wv /= sn;
            int g = gtcL[e];
            bool zero = pos ? (g < 20) : (g >= 10);
            if (zero) continue;
            float pa = predL[ea[e]], pb = predL[eb[e]];
            float fa_, fb_;
            if (!pos) { fa_ = pa * pa; fb_ = pb * pb; }
            else { float qa = 20.0f - pa, qb = 20.0f - pb; fa_ = qa * qa; fb_ = qb * qb; }
            lossAcc += (pos ? lrp : lr) * wv * (fa_ + fb_);
        }
        __syncthreads();
    }

    #pragma unroll
    for (int off = 32; off > 0; off >>= 1) lossAcc += __shfl_xor(lossAcc, off, 64);
    if (tid == 0) atomicAdd(out, lossAcc);
}

__global__ void zero_out_kernel(float* o)
{
    if (threadIdx.x == 0 && blockIdx.x == 0) o[0] = 0.0f;
}

extern "C" void kernel_launch(void* const* d_in, const int* in_sizes, int n_in,
                              void* d_out, int out_size, void* d_ws, size_t ws_size,
                              hipStream_t stream)
{
    const float* pred   = (const float*)d_in[0];
    const float* target = (const float*)d_in[1];
    const float* lr     = (const float*)d_in[2];
    const float* lrp    = (const float*)d_in[3];
    float* out = (float*)d_out;

    zero_out_kernel<<<1, 64, 0, stream>>>(out);
    malis_kernel<<<128, 64, 0, stream>>>(pred, target, lr, lrp, out);
}

// Round 2
// 1069.162 us; speedup vs baseline: 4.0415x; 4.0415x over previous
//
#include <hip/hip_runtime.h>
#include <cstdint>

#define NPIX  1024
#define NH    992
#define NEDGE 1984
#define NSORT 2048
#define NGRP  31

typedef unsigned long long u64;
typedef unsigned int u32;

static __device__ __forceinline__ u64 packRoot(int sN, int sL, int len, int hd, int tl) {
    return (u64)(u32)(sN & 0x7FF)
         | ((u64)(u32)(sL & 0x7FF) << 11)
         | ((u64)(u32)(len & 0x7FF) << 22)
         | ((u64)(u32)(hd & 0x7FF) << 33)
         | ((u64)(u32)(tl & 0x7FF) << 44);
}

__global__ __launch_bounds__(128) void malis_kernel(
    const float* __restrict__ pred,
    const float* __restrict__ target,
    const float* __restrict__ lr_p,
    const float* __restrict__ lrp_p,
    float* __restrict__ out)
{
    const int tid  = threadIdx.x;
    const int lane = tid & 63;
    const int wv   = tid >> 6;        // wave 0: negative pass, wave 1: positive pass
    const int bid  = blockIdx.x;
    const int bb   = bid >> 6;
    const int win  = bid & 63;
    const int wy   = win >> 3, wx = win & 7;
    const int base = bb * 65536 + (wy * 32) * 256 + wx * 32;

    // ---- LDS (~115 KB; 1 block/CU, 128 blocks <= 256 CUs) ----
    __shared__ u64   keys[2][NSORT];        // 32768  (overlaid early: masks+labId)
    __shared__ float W[2][NEDGE];           // 15872
    __shared__ float predL[NPIX];           // 4096
    __shared__ float costs[NEDGE];          // 7936
    __shared__ short seg[NPIX];             // 2048
    __shared__ u32   eab[NEDGE];            // 7936  a | b<<16
    __shared__ unsigned char tgtL[NPIX];    // 1024
    __shared__ unsigned char gtcL[NEDGE];   // 1984
    __shared__ short par[2][NPIX];          // 4096
    __shared__ u64   root[2][NPIX];         // 16384 packed {sN,sL,len,hd,tl}
    __shared__ u64   ent[2][NPIX];          // 16384 packed {nxt(16),lab(16),cnt(32)}
    __shared__ short H[2][NPIX + 1];        // 4100
    __shared__ u32   SP[2][64];             // 512   speculated (e,ra,rb)
    __shared__ int   flags[2];

    // early scratch overlaid on keys (dead until per-wave key build)
    unsigned char* mA    = (unsigned char*)keys;
    unsigned char* mB    = mA + NPIX;
    short*         labId = (short*)(mA + 2 * NPIX);

    // ---- load window ----
    for (int i = tid; i < NPIX; i += 128) {
        int r = i >> 5, c = i & 31;
        float pv = pred[base + r * 256 + c];
        float tv = target[base + r * 256 + c];
        predL[i] = pv;
        tgtL[i]  = (unsigned char)tv;
        mA[i]    = (tv == 0.0f) ? 1 : 0;
    }
    if (tid == 0) flags[1] = 0;
    __syncthreads();

    // ---- dilate 5x (4-neighborhood) ----
    unsigned char* srcm = mA;
    unsigned char* dstm = mB;
    for (int it = 0; it < 5; ++it) {
        for (int i = tid; i < NPIX; i += 128) {
            int r = i >> 5, c = i & 31;
            unsigned char v = srcm[i];
            if (r > 0)  v |= srcm[i - 32];
            if (r < 31) v |= srcm[i + 32];
            if (c > 0)  v |= srcm[i - 1];
            if (c < 31) v |= srcm[i + 1];
            dstm[i] = v;
        }
        __syncthreads();
        unsigned char* t2 = srcm; srcm = dstm; dstm = t2;
    }

    // ---- CCL (8-conn) on fg = !dilated: min-index propagation + pointer jumps ----
    for (int i = tid; i < NPIX; i += 128)
        seg[i] = srcm[i] ? (short)-1 : (short)i;
    __syncthreads();

    for (;;) {
        if (tid == 0) flags[0] = 0;
        __syncthreads();
        bool any = false;
        for (int i = tid; i < NPIX; i += 128) {
            int cur = seg[i];
            if (cur < 0) continue;
            int r = i >> 5, c = i & 31;
            int m = cur;
            if (r > 0) {
                if (c > 0)  { int t = seg[i - 33]; if (t >= 0 && t < m) m = t; }
                { int t = seg[i - 32]; if (t >= 0 && t < m) m = t; }
                if (c < 31) { int t = seg[i - 31]; if (t >= 0 && t < m) m = t; }
            }
            if (c > 0)  { int t = seg[i - 1]; if (t >= 0 && t < m) m = t; }
            if (c < 31) { int t = seg[i + 1]; if (t >= 0 && t < m) m = t; }
            if (r < 31) {
                if (c > 0)  { int t = seg[i + 31]; if (t >= 0 && t < m) m = t; }
                { int t = seg[i + 32]; if (t >= 0 && t < m) m = t; }
                if (c < 31) { int t = seg[i + 33]; if (t >= 0 && t < m) m = t; }
            }
            #pragma unroll
            for (int t2 = 0; t2 < 4; ++t2) {
                int s2 = seg[m];
                if (s2 >= 0 && s2 < m) m = s2; else break;
            }
            if (m < cur) { seg[i] = (short)m; any = true; }
        }
        if (any) flags[0] = 1;
        __syncthreads();
        if (flags[0] == 0) break;
        __syncthreads();
    }

    // compact label ids: seg -> 0 (bg) or 1..K
    for (int i = tid; i < NPIX; i += 128)
        if (seg[i] == (short)i) labId[i] = (short)atomicAdd(&flags[1], 1);
    __syncthreads();
    for (int i = tid; i < NPIX; i += 128) {
        short s2 = seg[i];
        seg[i] = (s2 < 0) ? (short)0 : (short)(labId[s2] + 1);
    }

    // ---- edges (reference order: 992 horizontal then 992 vertical) ----
    for (int e = tid; e < NEDGE; e += 128) {
        int a, b2;
        if (e < NH) { int r = e / 31, c = e - r * 31; a = r * 32 + c; b2 = a + 1; }
        else        { int q = e - NH; int r = q >> 5, c = q & 31; a = r * 32 + c; b2 = a + 32; }
        eab[e]   = (u32)a | ((u32)b2 << 16);
        costs[e] = predL[a] + predL[b2];
        gtcL[e]  = (unsigned char)(tgtL[a] + tgtL[b2]);
    }
    __syncthreads();

    // ================= per-wave: one MALIS phase each =================
    const int ph = wv;                 // 0 = neg, 1 = pos
    u64*   K     = keys[ph];
    float* Wp    = W[ph];
    short* par_  = par[ph];
    u64*   root_ = root[ph];
    u64*   ent_  = ent[ph];
    short* H_    = H[ph];
    u32*   SP_   = SP[ph];

    // keys: (~bits(cost))<<32 | e  => ascending == (cost desc, idx asc), exact ref order
    for (int e = lane; e < NEDGE; e += 64) {
        float cv = costs[e];
        int g = gtcL[e];
        if (ph == 0) { if (g > 20) cv = 20.0f; }
        else         { if (g < 10) cv = 0.0f; }
        u32 bits = __float_as_uint(cv);       // costs >= 0: monotone bit pattern
        K[e]  = (((u64)(~bits)) << 32) | (u32)e;
        Wp[e] = 0.0f;
    }
    for (int e = NEDGE + lane; e < NSORT; e += 64) K[e] = ~0ULL;

    for (int i = lane; i < NPIX; i += 64) {
        par_[i] = (short)i;
        short s2 = seg[i];
        if (s2) {
            root_[i] = packRoot(1, 1, 1, i, i);
            ent_[i]  = 0xFFFFull | ((u64)(u32)(unsigned short)s2 << 16) | (1ull << 32);
        } else {
            root_[i] = packRoot(1, 0, 0, -1, -1);
        }
        H_[i] = 0;
    }
    if (lane == 0) H_[NPIX] = 0;
    __syncthreads();

    // bitonic sort (each wave sorts its own 2048 keys; barrier counts identical)
    for (int kk = 2; kk <= NSORT; kk <<= 1) {
        for (int j = kk >> 1; j > 0; j >>= 1) {
            for (int i = lane; i < NSORT; i += 64) {
                int ixj = i ^ j;
                if (ixj > i) {
                    u64 x = K[i], y = K[ixj];
                    bool up = ((i & kk) == 0);
                    if ((x > y) == up) { K[i] = y; K[ixj] = x; }
                }
            }
            __syncthreads();
        }
    }

    // ---- Kruskal: wave-speculated finds + lane-0 serial merge (no block barriers) ----
    for (int g2 = 0; g2 < NGRP; ++g2) {
        // speculation: 64 lanes pre-resolve roots for the next 64 sorted edges.
        // Races in path compression are benign (any stored value is an ancestor;
        // no unions run during this phase). Stale roots are valid start points.
        {
            int s3 = g2 * 64 + lane;
            u64 kk2 = K[s3];
            int e  = (int)(u32)kk2;
            u32 ab = eab[e];
            int ra = (int)(ab & 0xFFFF);
            for (;;) { int p = par_[ra]; if (p == ra) break; int q = par_[p]; par_[ra] = (short)q; ra = q; }
            int rb = (int)(ab >> 16);
            for (;;) { int p = par_[rb]; if (p == rb) break; int q = par_[p]; par_[rb] = (short)q; rb = q; }
            SP_[lane] = (u32)e | ((u32)ra << 11) | ((u32)rb << 21);
        }
        if (lane == 0) {
            u32 vnext = SP_[0];
            for (int i = 0; i < 64; ++i) {
                u32 v = vnext;
                vnext = SP_[(i + 1) & 63];
                int e2  = (int)(v & 0x7FF);
                int ra2 = (int)((v >> 11) & 0x3FF);
                int rb2 = (int)((v >> 21) & 0x3FF);
                for (;;) { int p = par_[ra2]; if (p == ra2) break; ra2 = p; }
                for (;;) { int p = par_[rb2]; if (p == rb2) break; rb2 = p; }
                if (ra2 == rb2) continue;
                u64 RA = root_[ra2], RB = root_[rb2];
                int sNa = (int)(RA & 0x7FF), sLa = (int)((RA >> 11) & 0x7FF);
                int lenA = (int)((RA >> 22) & 0x7FF);
                int hdA = (int)((RA >> 33) & 0x7FF); if (hdA == 0x7FF) hdA = -1;
                int tlA = (int)((RA >> 44) & 0x7FF); if (tlA == 0x7FF) tlA = -1;
                int sNb = (int)(RB & 0x7FF), sLb = (int)((RB >> 11) & 0x7FF);
                int lenB = (int)((RB >> 22) & 0x7FF);
                int hdB = (int)((RB >> 33) & 0x7FF); if (hdB == 0x7FF) hdB = -1;
                int tlB = (int)((RB >> 44) & 0x7FF); if (tlB == 0x7FF) tlB = -1;

                int mHd, mTl, mLen;
                if (sLa > 0 && sLb > 0) {
                    int hdS, hdL2, lenL2;
                    if (lenA <= lenB) { hdS = hdA; hdL2 = hdB; lenL2 = lenB; }
                    else              { hdS = hdB; hdL2 = hdA; lenL2 = lenA; }
                    // phase1: hist smaller list's (label,count)
                    for (int p = hdS; p != -1;) {
                        u64 en = ent_[p];
                        H_[(int)((en >> 16) & 0xFFFF)] = (short)(en >> 32);
                        int nx = (int)(en & 0xFFFF);
                        p = (nx == 0xFFFF) ? -1 : nx;
                    }
                    // phase2: walk larger; same += h*c; absorb duplicate counts; consume H
                    int same = 0;
                    int lastIdx = -1; u64 lastEnt = 0;
                    for (int p = hdL2; p != -1;) {
                        u64 en = ent_[p];
                        int k3 = (int)((en >> 16) & 0xFFFF);
                        int h = H_[k3];
                        if (h) {
                            int c = (int)(en >> 32);
                            same += h * c;
                            en = (en & 0xFFFFFFFFull) | ((u64)(u32)(c + h) << 32);
                            ent_[p] = en;
                            H_[k3] = 0;
                        }
                        lastIdx = p; lastEnt = en;
                        int nx = (int)(en & 0xFFFF);
                        p = (nx == 0xFFFF) ? -1 : nx;
                    }
                    // phase3: append smaller's unique labels to larger; clear H
                    mHd = hdL2; mLen = lenL2;
                    int tail = lastIdx; u64 tailEnt = lastEnt;
                    for (int p = hdS; p != -1;) {
                        u64 en = ent_[p];
                        int nx0 = (int)(en & 0xFFFF);
                        int nxt2 = (nx0 == 0xFFFF) ? -1 : nx0;
                        int k3 = (int)((en >> 16) & 0xFFFF);
                        if (H_[k3]) {
                            H_[k3] = 0;
                            tailEnt = (tailEnt & ~(u64)0xFFFF) | (u32)tail; // keep fields
                            tailEnt = (tailEnt & ~(u64)0xFFFF) | (u32)p;
                            ent_[tail] = tailEnt;
                            en |= 0xFFFFull;                                // nxt = null
                            ent_[p] = en;
                            tail = p; tailEnt = en;
                            mLen++;
                        }
                        p = nxt2;
                    }
                    mTl = tail;
                    Wp[e2] = (float)(ph ? same : (sLa * sLb - same));
                } else if (sLa > 0) { mHd = hdA; mTl = tlA; mLen = lenA; }
                else if (sLb > 0)   { mHd = hdB; mTl = tlB; mLen = lenB; }
                else                { mHd = -1; mTl = -1; mLen = 0; }

                int winner, loser;
                if (sNa >= sNb) { winner = ra2; loser = rb2; }
                else            { winner = rb2; loser = ra2; }
                par_[loser] = (short)winner;
                root_[winner] = packRoot(sNa + sNb, sLa + sLb, mLen, mHd, mTl);
            }
        }
    }

    // ---- epilogue per wave ----
    float s_loc = 0.0f;
    for (int e = lane; e < NEDGE; e += 64) s_loc += Wp[e];
    #pragma unroll
    for (int off = 32; off > 0; off >>= 1) s_loc += __shfl_xor(s_loc, off, 64);
    const float sn = s_loc;

    const float scale = ph ? lrp_p[0] : lr_p[0];
    float acc = 0.0f;
    for (int e = lane; e < NEDGE; e += 64) {
        float wv2 = Wp[e];
        if (wv2 == 0.0f) continue;
        if (sn > 0.0f) wv2 /= sn;
        int g = gtcL[e];
        bool zero = ph ? (g < 20) : (g >= 10);
        if (zero) continue;
        u32 ab = eab[e];
        float pa = predL[ab & 0xFFFF], pb = predL[ab >> 16];
        float fa2, fb2;
        if (ph == 0) { fa2 = pa * pa; fb2 = pb * pb; }
        else { float qa = 20.0f - pa, qb = 20.0f - pb; fa2 = qa * qa; fb2 = qb * qb; }
        acc += scale * wv2 * (fa2 + fb2);
    }
    #pragma unroll
    for (int off = 32; off > 0; off >>= 1) acc += __shfl_xor(acc, off, 64);
    if (lane == 0) atomicAdd(out, acc);
}

__global__ void zero_out_kernel(float* o)
{
    if (threadIdx.x == 0 && blockIdx.x == 0) o[0] = 0.0f;
}

extern "C" void kernel_launch(void* const* d_in, const int* in_sizes, int n_in,
                              void* d_out, int out_size, void* d_ws, size_t ws_size,
                              hipStream_t stream)
{
    const float* pred   = (const float*)d_in[0];
    const float* target = (const float*)d_in[1];
    const float* lr     = (const float*)d_in[2];
    const float* lrp    = (const float*)d_in[3];
    float* out = (float*)d_out;

    zero_out_kernel<<<1, 64, 0, stream>>>(out);
    malis_kernel<<<128, 128, 0, stream>>>(pred, target, lr, lrp, out);
}

// Round 3
// 811.799 us; speedup vs baseline: 5.3228x; 1.3170x over previous
//
#include <hip/hip_runtime.h>
#include <cstdint>

#define NPIX  1024
#define NH    992
#define NEDGE 1984
#define NSORT 2048
#define NGRP  31
#define HFS   3300
#define POOLN (NPIX + 2*HFS)   // 7624 u32 entries per phase

typedef unsigned long long u64;
typedef unsigned int u32;

// root_ pack: sN[0,11) | sL[11,22) | off[22,35) | len[35,46) | cap[46,57)
static __device__ __forceinline__ u64 packRoot(int sN,int sL,int off,int len,int cap){
    return (u64)(u32)(sN & 0x7FF) | ((u64)(u32)(sL & 0x7FF) << 11) |
           ((u64)(u32)(off & 0x1FFF) << 22) | ((u64)(u32)(len & 0x7FF) << 35) |
           ((u64)(u32)(cap & 0x7FF) << 46);
}
#define R_SN(R)  ((int)((R) & 0x7FF))
#define R_SL(R)  ((int)(((R)>>11) & 0x7FF))
#define R_OFF(R) ((int)(((R)>>22) & 0x1FFF))
#define R_LEN(R) ((int)(((R)>>35) & 0x7FF))
#define R_CAP(R) ((int)(((R)>>46) & 0x7FF))

static __device__ __forceinline__ int wredi(int v){
    #pragma unroll
    for (int o = 32; o > 0; o >>= 1) v += __shfl_xor(v, o, 64);
    return v;
}
static __device__ __forceinline__ float wredf(float v){
    #pragma unroll
    for (int o = 32; o > 0; o >>= 1) v += __shfl_xor(v, o, 64);
    return v;
}

__global__ __launch_bounds__(128) void malis_kernel(
    const float* __restrict__ pred,
    const float* __restrict__ target,
    const float* __restrict__ lr_p,
    const float* __restrict__ lrp_p,
    float* __restrict__ out)
{
    const int tid  = threadIdx.x;
    const int lane = tid & 63;
    const int wv   = tid >> 6;        // wave 0: negative pass, wave 1: positive pass
    const int bid  = blockIdx.x;
    const int bb   = bid >> 6;
    const int win  = bid & 63;
    const int wy   = win >> 3, wx = win & 7;
    const int base = bb * 65536 + (wy * 32) * 256 + wx * 32;

    // ---- LDS (~159.3 KB; 1 block/CU) ----
    __shared__ u64   keys[2][NSORT];        // 32768 (overlaid early: masks+labId)
    __shared__ u64   root[2][NPIX];         // 16384
    __shared__ float W[2][NEDGE];           // 15872
    __shared__ float predL[NPIX];           // 4096
    __shared__ float costs[NEDGE];          // 7936
    __shared__ u32   eab[NEDGE];            // 7936  a | b<<16
    __shared__ u32   poolS[2][POOLN];       // 60992 label-count arrays {lab<<16|cnt}
    __shared__ short seg[NPIX];             // 2048
    __shared__ short par[2][NPIX];          // 4096
    __shared__ short H[2][NPIX + 1];        // 4100
    __shared__ unsigned char tgtL[NPIX];    // 1024
    __shared__ unsigned char gtcL[NEDGE];   // 1984
    __shared__ int   flags[2];

    // early scratch overlaid on keys (dead until per-wave key build)
    unsigned char* mA    = (unsigned char*)keys;
    unsigned char* mB    = mA + NPIX;
    short*         labId = (short*)(mA + 2 * NPIX);

    // ---- load window ----
    for (int i = tid; i < NPIX; i += 128) {
        int r = i >> 5, c = i & 31;
        float pv = pred[base + r * 256 + c];
        float tv = target[base + r * 256 + c];
        predL[i] = pv;
        tgtL[i]  = (unsigned char)tv;
        mA[i]    = (tv == 0.0f) ? 1 : 0;
    }
    if (tid == 0) flags[1] = 0;
    __syncthreads();

    // ---- dilate 5x (4-neighborhood) ----
    unsigned char* srcm = mA;
    unsigned char* dstm = mB;
    for (int it = 0; it < 5; ++it) {
        for (int i = tid; i < NPIX; i += 128) {
            int r = i >> 5, c = i & 31;
            unsigned char v = srcm[i];
            if (r > 0)  v |= srcm[i - 32];
            if (r < 31) v |= srcm[i + 32];
            if (c > 0)  v |= srcm[i - 1];
            if (c < 31) v |= srcm[i + 1];
            dstm[i] = v;
        }
        __syncthreads();
        unsigned char* t2 = srcm; srcm = dstm; dstm = t2;
    }

    // ---- CCL (8-conn) on fg = !dilated ----
    for (int i = tid; i < NPIX; i += 128)
        seg[i] = srcm[i] ? (short)-1 : (short)i;
    __syncthreads();

    for (;;) {
        if (tid == 0) flags[0] = 0;
        __syncthreads();
        bool any = false;
        for (int i = tid; i < NPIX; i += 128) {
            int cur = seg[i];
            if (cur < 0) continue;
            int r = i >> 5, c = i & 31;
            int m = cur;
            if (r > 0) {
                if (c > 0)  { int t = seg[i - 33]; if (t >= 0 && t < m) m = t; }
                { int t = seg[i - 32]; if (t >= 0 && t < m) m = t; }
                if (c < 31) { int t = seg[i - 31]; if (t >= 0 && t < m) m = t; }
            }
            if (c > 0)  { int t = seg[i - 1]; if (t >= 0 && t < m) m = t; }
            if (c < 31) { int t = seg[i + 1]; if (t >= 0 && t < m) m = t; }
            if (r < 31) {
                if (c > 0)  { int t = seg[i + 31]; if (t >= 0 && t < m) m = t; }
                { int t = seg[i + 32]; if (t >= 0 && t < m) m = t; }
                if (c < 31) { int t = seg[i + 33]; if (t >= 0 && t < m) m = t; }
            }
            #pragma unroll
            for (int t2 = 0; t2 < 4; ++t2) {
                int s2 = seg[m];
                if (s2 >= 0 && s2 < m) m = s2; else break;
            }
            if (m < cur) { seg[i] = (short)m; any = true; }
        }
        if (any) flags[0] = 1;
        __syncthreads();
        if (flags[0] == 0) break;
        __syncthreads();
    }

    // compact label ids: seg -> 0 (bg) or 1..K
    for (int i = tid; i < NPIX; i += 128)
        if (seg[i] == (short)i) labId[i] = (short)atomicAdd(&flags[1], 1);
    __syncthreads();
    for (int i = tid; i < NPIX; i += 128) {
        short s2 = seg[i];
        seg[i] = (s2 < 0) ? (short)0 : (short)(labId[s2] + 1);
    }

    // ---- edges (reference order: 992 horizontal then 992 vertical) ----
    for (int e = tid; e < NEDGE; e += 128) {
        int a, b2;
        if (e < NH) { int r = e / 31, c = e - r * 31; a = r * 32 + c; b2 = a + 1; }
        else        { int q = e - NH; int r = q >> 5, c = q & 31; a = r * 32 + c; b2 = a + 32; }
        eab[e]   = (u32)a | ((u32)b2 << 16);
        costs[e] = predL[a] + predL[b2];
        gtcL[e]  = (unsigned char)(tgtL[a] + tgtL[b2]);
    }
    __syncthreads();
    // ======== no block barriers below this line: waves fully decoupled ========

    const int ph = wv;                 // 0 = neg, 1 = pos
    u64*   K     = keys[ph];
    float* Wp    = W[ph];
    short* par_  = par[ph];
    u64*   root_ = root[ph];
    u32*   pool_ = poolS[ph];
    short* H_    = H[ph];

    // keys: (~bits(cost))<<32 | e  => ascending == (cost desc, idx asc) == ref order
    for (int e = lane; e < NEDGE; e += 64) {
        float cv = costs[e];
        int g = gtcL[e];
        if (ph == 0) { if (g > 20) cv = 20.0f; }
        else         { if (g < 10) cv = 0.0f; }
        u32 bits = __float_as_uint(cv);       // costs >= 0: monotone bit pattern
        K[e]  = (((u64)(~bits)) << 32) | (u32)e;
        Wp[e] = 0.0f;
    }
    for (int e = NEDGE + lane; e < NSORT; e += 64) K[e] = ~0ULL;  // sorts to tail, never processed

    // union-find init; labeled pixel i owns pool slot i = {seg[i], cnt 1}
    for (int i = lane; i < NPIX; i += 64) {
        par_[i] = (short)i;
        short s2 = seg[i];
        if (s2) {
            root_[i] = packRoot(1, 1, i, 1, 1);
            pool_[i] = ((u32)(unsigned short)s2 << 16) | 1u;
        } else {
            root_[i] = packRoot(1, 0, 0, 0, 0);
        }
        H_[i] = 0;
    }
    if (lane == 0) H_[NPIX] = 0;
    __builtin_amdgcn_wave_barrier();

    // bitonic sort, per-wave (same-wave DS ops are in-order; wave_barrier pins compiler)
    for (int kk = 2; kk <= NSORT; kk <<= 1) {
        for (int j = kk >> 1; j > 0; j >>= 1) {
            for (int i = lane; i < NSORT; i += 64) {
                int ixj = i ^ j;
                if (ixj > i) {
                    u64 x = K[i], y = K[ixj];
                    bool up = ((i & kk) == 0);
                    if ((x > y) == up) { K[i] = y; K[ixj] = x; }
                }
            }
            __builtin_amdgcn_wave_barrier();
        }
    }

    // ---- Kruskal: spec + sure-skip filter + cooperative merges ----
    u32 bump = NPIX;               // allocations start in half0
    u32 halfEnd = NPIX + HFS;
    int curHalf = 0;
    const u64 ltm = (1ull << lane) - 1;

    auto do_gc = [&]() {           // ping-pong compaction; live entries <= 1024 < HFS
        u32 tgt = (curHalf == 0) ? (u32)(NPIX + HFS) : (u32)NPIX;
        u32 nb = tgt;
        for (int c = 0; c < 16; ++c) {
            int i0 = c * 64 + lane;
            bool isr = (par_[i0] == (short)i0);
            u64 rbm = __ballot(isr);
            while (rbm) {
                int j = __ffsll(rbm) - 1; rbm &= rbm - 1;
                int r = c * 64 + j;
                u64 R = root_[r];
                int len = R_LEN(R);
                if (len) {
                    int off = R_OFF(R);
                    for (int t = lane; t < len; t += 64) {
                        u32 v2 = pool_[off + t];
                        pool_[nb + t] = v2;
                    }
                    __builtin_amdgcn_wave_barrier();
                    if (lane == 0) root_[r] = packRoot(R_SN(R), R_SL(R), (int)nb, len, len);
                    nb += (u32)len;
                }
            }
        }
        bump = nb;
        halfEnd = tgt + HFS;
        curHalf ^= 1;
    };

    for (int g2 = 0; g2 < NGRP; ++g2) {
        // spec: 64 lanes pre-resolve roots (path-halving races benign)
        int s3 = g2 * 64 + lane;
        u64 kk2 = K[s3];
        int e  = (int)(u32)kk2;
        u32 ab = eab[e];
        int ra = (int)(ab & 0xFFFF);
        for (;;) { int p = par_[ra]; if (p == ra) break; int q = par_[p]; par_[ra] = (short)q; ra = q; }
        int rb = (int)(ab >> 16);
        for (;;) { int p = par_[rb]; if (p == rb) break; int q = par_[p]; par_[rb] = (short)q; rb = q; }
        u32 myspec = (u32)e | ((u32)ra << 11) | ((u32)rb << 21);
        u64 bal = __ballot(ra != rb);        // sure-skips filtered out
        __builtin_amdgcn_wave_barrier();

        while (bal) {
            int srcl = __ffsll(bal) - 1; bal &= bal - 1;
            u32 v = (u32)__shfl((int)myspec, srcl);
            int e2  = (int)(v & 0x7FF);
            int sra = (int)((v >> 11) & 0x3FF);
            int srb = (int)((v >> 21) & 0x3FF);
            int pa = par_[sra], pb = par_[srb];   // parallel issue
            int ra2 = sra;
            if (pa != sra) { ra2 = pa; for (;;) { int p = par_[ra2]; if (p == ra2) break; ra2 = p; } }
            int rb2 = srb;
            if (pb != srb) { rb2 = pb; for (;;) { int p = par_[rb2]; if (p == rb2) break; rb2 = p; } }
            if (ra2 == rb2) continue;

            u64 RA = root_[ra2], RB = root_[rb2]; // parallel issue
            int sNa = R_SN(RA), sLa = R_SL(RA);
            int sNb = R_SN(RB), sLb = R_SL(RB);
            int dOff = 0, dLen = 0, dCap = 0;

            if (sLa > 0 && sLb > 0) {
                int lenA = R_LEN(RA), lenB = R_LEN(RB);
                if (bump + (u32)(lenA + lenB + 8) > halfEnd) {
                    do_gc();
                    RA = root_[ra2]; RB = root_[rb2];
                    lenA = R_LEN(RA); lenB = R_LEN(RB);
                }
                int offA = R_OFF(RA), capA = R_CAP(RA);
                int offB = R_OFF(RB), capB = R_CAP(RB);
                int offS, lenS, offL, lenL, capL;
                if (lenA <= lenB) { offS = offA; lenS = lenA; offL = offB; lenL = lenB; capL = capB; }
                else              { offS = offB; lenS = lenB; offL = offA; lenL = lenA; capL = capA; }
                int same;

                if (lenS == 1 && lenL == 1) {
                    u32 xS = pool_[offS];
                    u32 xL = pool_[offL];
                    if ((xS >> 16) == (xL >> 16)) {
                        same = (int)(xS & 0xFFFF) * (int)(xL & 0xFFFF);
                        if (lane == 0) pool_[offL] = xL + (xS & 0xFFFF);
                        dOff = offL; dLen = 1; dCap = capL;
                    } else {
                        same = 0;
                        dOff = (int)bump; dLen = 2; dCap = 8; bump += 8;
                        if (lane == 0) { pool_[dOff] = xL; pool_[dOff + 1] = xS; }
                    }
                } else if (lenS == 1 && lenL <= 64) {
                    u32 xS = pool_[offS];
                    u32 eL = (lane < lenL) ? pool_[offL + lane] : 0u;
                    bool match = (lane < lenL) && ((eL >> 16) == (xS >> 16));
                    u64 mb = __ballot(match);
                    if (mb) {
                        int ml = __ffsll(mb) - 1;
                        u32 eM = (u32)__shfl((int)eL, ml);
                        same = (int)(xS & 0xFFFF) * (int)(eM & 0xFFFF);
                        if (match) pool_[offL + lane] = eL + (xS & 0xFFFF);
                        dOff = offL; dLen = lenL; dCap = capL;
                    } else {
                        same = 0;
                        if (lenL < capL) {
                            if (lane == 0) pool_[offL + lenL] = xS;
                            dOff = offL; dLen = lenL + 1; dCap = capL;
                        } else {
                            dOff = (int)bump; dLen = lenL + 1; dCap = (dLen + 4) & ~3; bump += (u32)dCap;
                            if (lane < lenL) pool_[dOff + lane] = eL;
                            if (lane == 0)   pool_[dOff + lenL] = xS;
                        }
                    }
                } else if (lenL <= 64) {
                    // general fast: 2 <= lenS <= lenL <= 64, histogram in H_
                    u32 eS = (lane < lenS) ? pool_[offS + lane] : 0u;
                    u32 eL = (lane < lenL) ? pool_[offL + lane] : 0u;
                    if (lane < lenS) H_[eS >> 16] = (short)(eS & 0xFFFF);
                    __builtin_amdgcn_wave_barrier();
                    int h = (lane < lenL) ? (int)H_[eL >> 16] : 0;
                    same = wredi(h * (int)(eL & 0xFFFF));
                    bool hit = (lane < lenL) && (h != 0);
                    if (hit) H_[eL >> 16] = 0;          // consume matched
                    __builtin_amdgcn_wave_barrier();
                    int h2 = (lane < lenS) ? (int)H_[eS >> 16] : 0;
                    bool un = (h2 != 0);                 // small label not in large
                    u64 ub = __ballot(un);
                    int U = __popcll(ub);
                    if (U == 0 || lenL + U <= capL) { dOff = offL; dCap = capL; }
                    else { dOff = (int)bump; dCap = (lenL + U + 4) & ~3; bump += (u32)dCap; }
                    dLen = lenL + U;
                    if (lane < lenL) pool_[dOff + lane] = eL + (u32)h;
                    if (un) {
                        int pos = __popcll(ub & ltm);
                        pool_[dOff + lenL + pos] = eS;
                        H_[eS >> 16] = 0;
                    }
                } else {
                    // slow generic (lenL > 64): stride loops, always-alloc upper bound
                    dOff = (int)bump;
                    dCap = (lenL + lenS + 4) & ~3; bump += (u32)dCap;
                    for (int j = lane; j < lenS; j += 64) {
                        u32 es = pool_[offS + j];
                        H_[es >> 16] = (short)(es & 0xFFFF);
                    }
                    __builtin_amdgcn_wave_barrier();
                    int sp = 0;
                    for (int j = lane; j < lenL; j += 64) {
                        u32 el = pool_[offL + j];
                        int h = (int)H_[el >> 16];
                        sp += h * (int)(el & 0xFFFF);
                        pool_[dOff + j] = el + (u32)h;
                        if (h) H_[el >> 16] = 0;
                    }
                    same = wredi(sp);
                    __builtin_amdgcn_wave_barrier();
                    int baseU = 0;
                    for (int j0 = 0; j0 < lenS; j0 += 64) {
                        int j = j0 + lane;
                        bool un = false; u32 es = 0;
                        if (j < lenS) { es = pool_[offS + j]; un = (H_[es >> 16] != 0); }
                        u64 ub = __ballot(un);
                        if (un) {
                            int pos = __popcll(ub & ltm);
                            pool_[dOff + lenL + baseU + pos] = es;
                            H_[es >> 16] = 0;
                        }
                        baseU += __popcll(ub);
                    }
                    dLen = lenL + baseU;
                }
                if (lane == 0) Wp[e2] = (float)(ph ? same : (sLa * sLb - same));
            } else if (sLa > 0) { dOff = R_OFF(RA); dLen = R_LEN(RA); dCap = R_CAP(RA); }
            else if (sLb > 0)   { dOff = R_OFF(RB); dLen = R_LEN(RB); dCap = R_CAP(RB); }

            int winner, loser;
            if (sNa >= sNb) { winner = ra2; loser = rb2; }
            else            { winner = rb2; loser = ra2; }
            if (lane == 0) {
                par_[loser]   = (short)winner;
                root_[winner] = packRoot(sNa + sNb, sLa + sLb, dOff, dLen, dCap);
            }
            __builtin_amdgcn_wave_barrier();
        }
    }

    // ---- epilogue per wave ----
    float s_loc = 0.0f;
    for (int e = lane; e < NEDGE; e += 64) s_loc += Wp[e];
    const float sn = wredf(s_loc);

    const float scale = ph ? lrp_p[0] : lr_p[0];
    float acc = 0.0f;
    for (int e = lane; e < NEDGE; e += 64) {
        float wv2 = Wp[e];
        if (wv2 == 0.0f) continue;
        if (sn > 0.0f) wv2 /= sn;
        int g = gtcL[e];
        bool zero = ph ? (g < 20) : (g >= 10);
        if (zero) continue;
        u32 ab = eab[e];
        float pa = predL[ab & 0xFFFF], pb = predL[ab >> 16];
        float fa2, fb2;
        if (ph == 0) { fa2 = pa * pa; fb2 = pb * pb; }
        else { float qa = 20.0f - pa, qb = 20.0f - pb; fa2 = qa * qa; fb2 = qb * qb; }
        acc += scale * wv2 * (fa2 + fb2);
    }
    acc = wredf(acc);
    if (lane == 0) atomicAdd(out, acc);
}

__global__ void zero_out_kernel(float* o)
{
    if (threadIdx.x == 0 && blockIdx.x == 0) o[0] = 0.0f;
}

extern "C" void kernel_launch(void* const* d_in, const int* in_sizes, int n_in,
                              void* d_out, int out_size, void* d_ws, size_t ws_size,
                              hipStream_t stream)
{
    const float* pred   = (const float*)d_in[0];
    const float* target = (const float*)d_in[1];
    const float* lr     = (const float*)d_in[2];
    const float* lrp    = (const float*)d_in[3];
    float* out = (float*)d_out;

    zero_out_kernel<<<1, 64, 0, stream>>>(out);
    malis_kernel<<<128, 128, 0, stream>>>(pred, target, lr, lrp, out);
}

// Round 4
// 681.861 us; speedup vs baseline: 6.3372x; 1.1906x over previous
//
#include <hip/hip_runtime.h>
#include <cstdint>

#define NPIX  1024
#define NH    992
#define NEDGE 1984
#define NSORT 2048
#define NGRP  31
#define HFS   3300
#define POOLN (NPIX + 2*HFS)   // 7624 u32 entries per phase

typedef unsigned long long u64;
typedef unsigned int u32;

// root_ pack: sN[0,11) | sL[11,22) | off[22,35) | len[35,46) | cap[46,57)
static __device__ __forceinline__ u64 packRoot(int sN,int sL,int off,int len,int cap){
    return (u64)(u32)(sN & 0x7FF) | ((u64)(u32)(sL & 0x7FF) << 11) |
           ((u64)(u32)(off & 0x1FFF) << 22) | ((u64)(u32)(len & 0x7FF) << 35) |
           ((u64)(u32)(cap & 0x7FF) << 46);
}
#define R_SN(R)  ((int)((R) & 0x7FF))
#define R_SL(R)  ((int)(((R)>>11) & 0x7FF))
#define R_OFF(R) ((int)(((R)>>22) & 0x1FFF))
#define R_LEN(R) ((int)(((R)>>35) & 0x7FF))
#define R_CAP(R) ((int)(((R)>>46) & 0x7FF))

static __device__ __forceinline__ int wredi(int v){
    #pragma unroll
    for (int o = 32; o > 0; o >>= 1) v += __shfl_xor(v, o, 64);
    return v;
}
static __device__ __forceinline__ float wredf(float v){
    #pragma unroll
    for (int o = 32; o > 0; o >>= 1) v += __shfl_xor(v, o, 64);
    return v;
}

__global__ __launch_bounds__(128) void malis_kernel(
    const float* __restrict__ pred,
    const float* __restrict__ target,
    const float* __restrict__ lr_p,
    const float* __restrict__ lrp_p,
    float* __restrict__ out)
{
    const int tid  = threadIdx.x;
    const int lane = tid & 63;
    const int wv   = tid >> 6;        // wave 0: negative pass, wave 1: positive pass
    const int bid  = blockIdx.x;
    const int bb   = bid >> 6;
    const int win  = bid & 63;
    const int wy   = win >> 3, wx = win & 7;
    const int base = bb * 65536 + (wy * 32) * 256 + wx * 32;

    // ---- LDS (~159 KB; 1 block/CU) ----
    __shared__ u64   keys[2][NSORT];        // 32768 (overlaid early: masks+labId)
    __shared__ u64   root[2][NPIX];         // 16384
    __shared__ float W[2][NEDGE];           // 15872
    __shared__ float predL[NPIX];           // 4096
    __shared__ float costs[NEDGE];          // 7936
    __shared__ u32   eab[NEDGE];            // 7936  a | b<<16
    __shared__ u32   poolS[2][POOLN];       // 60992 label-count arrays {lab<<16|cnt}
    __shared__ short seg[NPIX];             // 2048
    __shared__ short par[2][NPIX];          // 4096
    __shared__ short H[2][NPIX + 1];        // 4100
    __shared__ unsigned char tgtL[NPIX];    // 1024
    __shared__ unsigned char gtcL[NEDGE];   // 1984
    __shared__ int   flags[2];

    // early scratch overlaid on keys (dead until per-wave key build)
    unsigned char* mA    = (unsigned char*)keys;
    unsigned char* mB    = mA + NPIX;
    short*         labId = (short*)(mA + 2 * NPIX);

    // ---- load window ----
    for (int i = tid; i < NPIX; i += 128) {
        int r = i >> 5, c = i & 31;
        float pv = pred[base + r * 256 + c];
        float tv = target[base + r * 256 + c];
        predL[i] = pv;
        tgtL[i]  = (unsigned char)tv;
        mA[i]    = (tv == 0.0f) ? 1 : 0;
    }
    if (tid == 0) flags[1] = 0;
    __syncthreads();

    // ---- dilate 5x (4-neighborhood) ----
    unsigned char* srcm = mA;
    unsigned char* dstm = mB;
    for (int it = 0; it < 5; ++it) {
        for (int i = tid; i < NPIX; i += 128) {
            int r = i >> 5, c = i & 31;
            unsigned char v = srcm[i];
            if (r > 0)  v |= srcm[i - 32];
            if (r < 31) v |= srcm[i + 32];
            if (c > 0)  v |= srcm[i - 1];
            if (c < 31) v |= srcm[i + 1];
            dstm[i] = v;
        }
        __syncthreads();
        unsigned char* t2 = srcm; srcm = dstm; dstm = t2;
    }

    // ---- CCL (8-conn) on fg = !dilated ----
    for (int i = tid; i < NPIX; i += 128)
        seg[i] = srcm[i] ? (short)-1 : (short)i;
    __syncthreads();

    for (;;) {
        if (tid == 0) flags[0] = 0;
        __syncthreads();
        bool any = false;
        for (int i = tid; i < NPIX; i += 128) {
            int cur = seg[i];
            if (cur < 0) continue;
            int r = i >> 5, c = i & 31;
            int m = cur;
            if (r > 0) {
                if (c > 0)  { int t = seg[i - 33]; if (t >= 0 && t < m) m = t; }
                { int t = seg[i - 32]; if (t >= 0 && t < m) m = t; }
                if (c < 31) { int t = seg[i - 31]; if (t >= 0 && t < m) m = t; }
            }
            if (c > 0)  { int t = seg[i - 1]; if (t >= 0 && t < m) m = t; }
            if (c < 31) { int t = seg[i + 1]; if (t >= 0 && t < m) m = t; }
            if (r < 31) {
                if (c > 0)  { int t = seg[i + 31]; if (t >= 0 && t < m) m = t; }
                { int t = seg[i + 32]; if (t >= 0 && t < m) m = t; }
                if (c < 31) { int t = seg[i + 33]; if (t >= 0 && t < m) m = t; }
            }
            #pragma unroll
            for (int t2 = 0; t2 < 6; ++t2) {
                int s2 = seg[m];
                if (s2 >= 0 && s2 < m) m = s2; else break;
            }
            if (m < cur) { seg[i] = (short)m; any = true; }
        }
        if (any) flags[0] = 1;
        __syncthreads();
        if (flags[0] == 0) break;
        __syncthreads();
    }

    // compact label ids: seg -> 0 (bg) or 1..K
    for (int i = tid; i < NPIX; i += 128)
        if (seg[i] == (short)i) labId[i] = (short)atomicAdd(&flags[1], 1);
    __syncthreads();
    for (int i = tid; i < NPIX; i += 128) {
        short s2 = seg[i];
        seg[i] = (s2 < 0) ? (short)0 : (short)(labId[s2] + 1);
    }

    // ---- edges (reference order: 992 horizontal then 992 vertical) ----
    for (int e = tid; e < NEDGE; e += 128) {
        int a, b2;
        if (e < NH) { int r = e / 31, c = e - r * 31; a = r * 32 + c; b2 = a + 1; }
        else        { int q = e - NH; int r = q >> 5, c = q & 31; a = r * 32 + c; b2 = a + 32; }
        eab[e]   = (u32)a | ((u32)b2 << 16);
        costs[e] = predL[a] + predL[b2];
        gtcL[e]  = (unsigned char)(tgtL[a] + tgtL[b2]);
    }
    __syncthreads();
    // ======== no block barriers below this line: waves fully decoupled ========

    const int ph = wv;                 // 0 = neg, 1 = pos
    u64*   K     = keys[ph];
    float* Wp    = W[ph];
    short* par_  = par[ph];
    u64*   root_ = root[ph];
    u32*   pool_ = poolS[ph];
    short* H_    = H[ph];

    // keys: (~bits(cost))<<32 | e  => ascending == (cost desc, idx asc) == ref order
    for (int e = lane; e < NEDGE; e += 64) {
        float cv = costs[e];
        int g = gtcL[e];
        if (ph == 0) { if (g > 20) cv = 20.0f; }
        else         { if (g < 10) cv = 0.0f; }
        u32 bits = __float_as_uint(cv);       // costs >= 0: monotone bit pattern
        K[e]  = (((u64)(~bits)) << 32) | (u32)e;
        Wp[e] = 0.0f;
    }
    for (int e = NEDGE + lane; e < NSORT; e += 64) K[e] = ~0ULL;  // tail, never processed

    // union-find init; labeled pixel i owns pool slot i = {seg[i], cnt 1}
    for (int i = lane; i < NPIX; i += 64) {
        par_[i] = (short)i;
        short s2 = seg[i];
        if (s2) {
            root_[i] = packRoot(1, 1, i, 1, 1);
            pool_[i] = ((u32)(unsigned short)s2 << 16) | 1u;
        } else {
            root_[i] = packRoot(1, 0, 0, 0, 0);
        }
        H_[i] = 0;
    }
    if (lane == 0) H_[NPIX] = 0;
    __builtin_amdgcn_wave_barrier();

    // bitonic sort, per-wave (same-wave DS ops are in-order; wave_barrier pins compiler)
    for (int kk = 2; kk <= NSORT; kk <<= 1) {
        for (int j = kk >> 1; j > 0; j >>= 1) {
            for (int i = lane; i < NSORT; i += 64) {
                int ixj = i ^ j;
                if (ixj > i) {
                    u64 x = K[i], y = K[ixj];
                    bool up = ((i & kk) == 0);
                    if ((x > y) == up) { K[i] = y; K[ixj] = x; }
                }
            }
            __builtin_amdgcn_wave_barrier();
        }
    }

    // ---- Kruskal: spec + register-resident roots; serial iters == merges only ----
    u32 bump = NPIX;               // allocations start in half0
    u32 halfEnd = NPIX + HFS;
    int curHalf = 0;
    const u64 ltm = (1ull << lane) - 1;

    auto do_gc = [&]() {           // ping-pong compaction; live entries <= 1024 < HFS
        u32 tgt = (curHalf == 0) ? (u32)(NPIX + HFS) : (u32)NPIX;
        u32 nb = tgt;
        for (int c = 0; c < 16; ++c) {
            int i0 = c * 64 + lane;
            bool isr = (par_[i0] == (short)i0);
            u64 rbm = __ballot(isr);
            while (rbm) {
                int j = __ffsll(rbm) - 1; rbm &= rbm - 1;
                int r = c * 64 + j;
                u64 R = root_[r];
                int len = R_LEN(R);
                if (len) {
                    int off = R_OFF(R);
                    for (int t = lane; t < len; t += 64) {
                        u32 v2 = pool_[off + t];
                        pool_[nb + t] = v2;
                    }
                    __builtin_amdgcn_wave_barrier();
                    if (lane == 0) root_[r] = packRoot(R_SN(R), R_SL(R), (int)nb, len, len);
                    nb += (u32)len;
                }
            }
        }
        bump = nb;
        halfEnd = tgt + HFS;
        curHalf ^= 1;
    };

    for (int g2 = 0; g2 < NGRP; ++g2) {
        // spec: resolve true roots for the group's 64 edges (all prior merges done).
        // Path-halving races are benign (any stored value is an ancestor).
        int myE;
        int ra, rb;
        {
            int s3 = g2 * 64 + lane;
            myE = (int)(u32)K[s3];
            u32 ab = eab[myE];
            ra = (int)(ab & 0xFFFF);
            for (;;) { int p = par_[ra]; if (p == ra) break; int q = par_[p]; par_[ra] = (short)q; ra = q; }
            rb = (int)(ab >> 16);
            for (;;) { int p = par_[rb]; if (p == rb) break; int q = par_[p]; par_[rb] = (short)q; rb = q; }
        }
        bool alive = (ra != rb);
        __builtin_amdgcn_wave_barrier();

        for (;;) {
            u64 bal = __ballot(alive);
            if (!bal) break;
            int srcl = __ffsll(bal) - 1;            // lowest lane == sorted order
            int mra = __shfl(ra, srcl);
            int mrb = __shfl(rb, srcl);
            int me  = __shfl(myE, srcl);

            u64 RA = root_[mra], RB = root_[mrb];    // broadcast reads, parallel issue
            int sNa = R_SN(RA), sLa = R_SL(RA);
            int sNb = R_SN(RB), sLb = R_SL(RB);
            int dOff = 0, dLen = 0, dCap = 0;

            if (sLa > 0 && sLb > 0) {
                int lenA = R_LEN(RA), lenB = R_LEN(RB);
                if (bump + (u32)(lenA + lenB + 8) > halfEnd) {
                    do_gc();
                    RA = root_[mra]; RB = root_[mrb];
                    lenA = R_LEN(RA); lenB = R_LEN(RB);
                }
                int offA = R_OFF(RA), capA = R_CAP(RA);
                int offB = R_OFF(RB), capB = R_CAP(RB);
                int offS, lenS, offL, lenL, capL;
                if (lenA <= lenB) { offS = offA; lenS = lenA; offL = offB; lenL = lenB; capL = capB; }
                else              { offS = offB; lenS = lenB; offL = offA; lenL = lenA; capL = capA; }
                int same;

                if (lenS == 1 && lenL == 1) {
                    u32 xS = pool_[offS];
                    u32 xL = pool_[offL];
                    if ((xS >> 16) == (xL >> 16)) {
                        same = (int)(xS & 0xFFFF) * (int)(xL & 0xFFFF);
                        if (lane == 0) pool_[offL] = xL + (xS & 0xFFFF);
                        dOff = offL; dLen = 1; dCap = capL;
                    } else {
                        same = 0;
                        dOff = (int)bump; dLen = 2; dCap = 8; bump += 8;
                        if (lane == 0) { pool_[dOff] = xL; pool_[dOff + 1] = xS; }
                    }
                } else if (lenS == 1 && lenL <= 64) {
                    u32 xS = pool_[offS];
                    u32 eL = (lane < lenL) ? pool_[offL + lane] : 0u;
                    bool match = (lane < lenL) && ((eL >> 16) == (xS >> 16));
                    u64 mb = __ballot(match);
                    if (mb) {
                        int ml = __ffsll(mb) - 1;
                        u32 eM = (u32)__shfl((int)eL, ml);
                        same = (int)(xS & 0xFFFF) * (int)(eM & 0xFFFF);
                        if (match) pool_[offL + lane] = eL + (xS & 0xFFFF);
                        dOff = offL; dLen = lenL; dCap = capL;
                    } else {
                        same = 0;
                        if (lenL < capL) {
                            if (lane == 0) pool_[offL + lenL] = xS;
                            dOff = offL; dLen = lenL + 1; dCap = capL;
                        } else {
                            dOff = (int)bump; dLen = lenL + 1; dCap = (dLen + 4) & ~3; bump += (u32)dCap;
                            if (lane < lenL) pool_[dOff + lane] = eL;
                            if (lane == 0)   pool_[dOff + lenL] = xS;
                        }
                    }
                } else if (lenL <= 64) {
                    // general fast: 2 <= lenS <= lenL <= 64, histogram in H_
                    u32 eS = (lane < lenS) ? pool_[offS + lane] : 0u;
                    u32 eL = (lane < lenL) ? pool_[offL + lane] : 0u;
                    if (lane < lenS) H_[eS >> 16] = (short)(eS & 0xFFFF);
                    __builtin_amdgcn_wave_barrier();
                    int h = (lane < lenL) ? (int)H_[eL >> 16] : 0;
                    same = wredi(h * (int)(eL & 0xFFFF));
                    bool hit = (lane < lenL) && (h != 0);
                    if (hit) H_[eL >> 16] = 0;          // consume matched
                    __builtin_amdgcn_wave_barrier();
                    int h2 = (lane < lenS) ? (int)H_[eS >> 16] : 0;
                    bool un = (h2 != 0);                 // small label not in large
                    u64 ub = __ballot(un);
                    int U = __popcll(ub);
                    if (U == 0 || lenL + U <= capL) { dOff = offL; dCap = capL; }
                    else { dOff = (int)bump; dCap = (lenL + U + 4) & ~3; bump += (u32)dCap; }
                    dLen = lenL + U;
                    if (lane < lenL) pool_[dOff + lane] = eL + (u32)h;
                    if (un) {
                        int pos = __popcll(ub & ltm);
                        pool_[dOff + lenL + pos] = eS;
                        H_[eS >> 16] = 0;
                    }
                } else {
                    // slow generic (lenL > 64): stride loops, always-alloc upper bound
                    dOff = (int)bump;
                    dCap = (lenL + lenS + 4) & ~3; bump += (u32)dCap;
                    for (int j = lane; j < lenS; j += 64) {
                        u32 es = pool_[offS + j];
                        H_[es >> 16] = (short)(es & 0xFFFF);
                    }
                    __builtin_amdgcn_wave_barrier();
                    int sp = 0;
                    for (int j = lane; j < lenL; j += 64) {
                        u32 el = pool_[offL + j];
                        int h = (int)H_[el >> 16];
                        sp += h * (int)(el & 0xFFFF);
                        pool_[dOff + j] = el + (u32)h;
                        if (h) H_[el >> 16] = 0;
                    }
                    same = wredi(sp);
                    __builtin_amdgcn_wave_barrier();
                    int baseU = 0;
                    for (int j0 = 0; j0 < lenS; j0 += 64) {
                        int j = j0 + lane;
                        bool un = false; u32 es = 0;
                        if (j < lenS) { es = pool_[offS + j]; un = (H_[es >> 16] != 0); }
                        u64 ub = __ballot(un);
                        if (un) {
                            int pos = __popcll(ub & ltm);
                            pool_[dOff + lenL + baseU + pos] = es;
                            H_[es >> 16] = 0;
                        }
                        baseU += __popcll(ub);
                    }
                    dLen = lenL + baseU;
                }
                if (lane == 0) Wp[me] = (float)(ph ? same : (sLa * sLb - same));
            } else if (sLa > 0) { dOff = R_OFF(RA); dLen = R_LEN(RA); dCap = R_CAP(RA); }
            else if (sLb > 0)   { dOff = R_OFF(RB); dLen = R_LEN(RB); dCap = R_CAP(RB); }

            int winner, loser;
            if (sNa >= sNb) { winner = mra; loser = mrb; }
            else            { winner = mrb; loser = mra; }
            if (lane == 0) {
                par_[loser]   = (short)winner;               // for next group's spec
                root_[winner] = packRoot(sNa + sNb, sLa + sLb, dOff, dLen, dCap);
            }
            // register-resident relabel: no finds, collisions die for free
            if (lane == srcl) alive = false;
            if (ra == loser) ra = winner;
            if (rb == loser) rb = winner;
            if (ra == rb) alive = false;
            __builtin_amdgcn_wave_barrier();
        }
    }

    // ---- epilogue per wave ----
    float s_loc = 0.0f;
    for (int e = lane; e < NEDGE; e += 64) s_loc += Wp[e];
    const float sn = wredf(s_loc);

    const float scale = ph ? lrp_p[0] : lr_p[0];
    float acc = 0.0f;
    for (int e = lane; e < NEDGE; e += 64) {
        float wv2 = Wp[e];
        if (wv2 == 0.0f) continue;
        if (sn > 0.0f) wv2 /= sn;
        int g = gtcL[e];
        bool zero = ph ? (g < 20) : (g >= 10);
        if (zero) continue;
        u32 ab = eab[e];
        float pa = predL[ab & 0xFFFF], pb = predL[ab >> 16];
        float fa2, fb2;
        if (ph == 0) { fa2 = pa * pa; fb2 = pb * pb; }
        else { float qa = 20.0f - pa, qb = 20.0f - pb; fa2 = qa * qa; fb2 = qb * qb; }
        acc += scale * wv2 * (fa2 + fb2);
    }
    acc = wredf(acc);
    if (lane == 0) atomicAdd(out, acc);
}

__global__ void zero_out_kernel(float* o)
{
    if (threadIdx.x == 0 && blockIdx.x == 0) o[0] = 0.0f;
}

extern "C" void kernel_launch(void* const* d_in, const int* in_sizes, int n_in,
                              void* d_out, int out_size, void* d_ws, size_t ws_size,
                              hipStream_t stream)
{
    const float* pred   = (const float*)d_in[0];
    const float* target = (const float*)d_in[1];
    const float* lr     = (const float*)d_in[2];
    const float* lrp    = (const float*)d_in[3];
    float* out = (float*)d_out;

    zero_out_kernel<<<1, 64, 0, stream>>>(out);
    malis_kernel<<<128, 128, 0, stream>>>(pred, target, lr, lrp, out);
}

// Round 5
// 620.170 us; speedup vs baseline: 6.9675x; 1.0995x over previous
//
#include <hip/hip_runtime.h>
#include <cstdint>

#define NPIX  1024
#define NH    992
#define NEDGE 1984
#define NSORT 2048
#define NGRP  31
#define HFS   3300
#define POOLN (NPIX + 2*HFS)   // 7624 u32 entries per phase

typedef unsigned long long u64;
typedef unsigned int u32;

// root_ pack (labeled roots only): sL[0,11) | off[11,24) | len[24,35) | cap[35,46)
static __device__ __forceinline__ u64 packRoot(int sL,int off,int len,int cap){
    return (u64)(u32)(sL & 0x7FF) | ((u64)(u32)(off & 0x1FFF) << 11) |
           ((u64)(u32)(len & 0x7FF) << 24) | ((u64)(u32)(cap & 0x7FF) << 35);
}
#define R_SL(R)  ((int)((R) & 0x7FF))
#define R_OFF(R) ((int)(((R)>>11) & 0x1FFF))
#define R_LEN(R) ((int)(((R)>>24) & 0x7FF))
#define R_CAP(R) ((int)(((R)>>35) & 0x7FF))

static __device__ __forceinline__ int rdl(int v, int l){ return __builtin_amdgcn_readlane(v, l); }

static __device__ __forceinline__ int wredi(int v){
    #pragma unroll
    for (int o = 32; o > 0; o >>= 1) v += __shfl_xor(v, o, 64);
    return v;
}
static __device__ __forceinline__ float wredf(float v){
    #pragma unroll
    for (int o = 32; o > 0; o >>= 1) v += __shfl_xor(v, o, 64);
    return v;
}

__global__ __launch_bounds__(128) void malis_kernel(
    const float* __restrict__ pred,
    const float* __restrict__ target,
    const float* __restrict__ lr_p,
    const float* __restrict__ lrp_p,
    float* __restrict__ out)
{
    const int tid  = threadIdx.x;
    const int lane = tid & 63;
    const int wv   = tid >> 6;        // wave 0: negative pass, wave 1: positive pass
    const int bid  = blockIdx.x;
    const int bb   = bid >> 6;
    const int win  = bid & 63;
    const int wy   = win >> 3, wx = win & 7;
    const int base = bb * 65536 + (wy * 32) * 256 + wx * 32;

    // ---- LDS (~159 KB; 1 block/CU) ----
    __shared__ u64   keys[2][NSORT];        // 32768 (overlaid early: masks+labId)
    __shared__ u64   root[2][NPIX];         // 16384
    __shared__ float W[2][NEDGE];           // 15872
    __shared__ float predL[NPIX];           // 4096
    __shared__ float costs[NEDGE];          // 7936
    __shared__ u32   eab[NEDGE];            // 7936  a | b<<16
    __shared__ u32   poolS[2][POOLN];       // 60992 label-count arrays {lab<<16|cnt}
    __shared__ short seg[NPIX];             // 2048
    __shared__ short par[2][NPIX];          // 4096
    __shared__ short H[2][NPIX + 1];        // 4100
    __shared__ unsigned char tgtL[NPIX];    // 1024
    __shared__ unsigned char gtcL[NEDGE];   // 1984
    __shared__ int   flags[2];

    // early scratch overlaid on keys (dead until per-wave key build)
    unsigned char* mA    = (unsigned char*)keys;
    unsigned char* mB    = mA + NPIX;
    short*         labId = (short*)(mA + 2 * NPIX);

    // ---- load window ----
    for (int i = tid; i < NPIX; i += 128) {
        int r = i >> 5, c = i & 31;
        float pv = pred[base + r * 256 + c];
        float tv = target[base + r * 256 + c];
        predL[i] = pv;
        tgtL[i]  = (unsigned char)tv;
        mA[i]    = (tv == 0.0f) ? 1 : 0;
    }
    if (tid == 0) flags[1] = 0;
    __syncthreads();

    // ---- dilate 5x (4-neighborhood) ----
    unsigned char* srcm = mA;
    unsigned char* dstm = mB;
    for (int it = 0; it < 5; ++it) {
        for (int i = tid; i < NPIX; i += 128) {
            int r = i >> 5, c = i & 31;
            unsigned char v = srcm[i];
            if (r > 0)  v |= srcm[i - 32];
            if (r < 31) v |= srcm[i + 32];
            if (c > 0)  v |= srcm[i - 1];
            if (c < 31) v |= srcm[i + 1];
            dstm[i] = v;
        }
        __syncthreads();
        unsigned char* t2 = srcm; srcm = dstm; dstm = t2;
    }

    // ---- CCL (8-conn) on fg = !dilated ----
    for (int i = tid; i < NPIX; i += 128)
        seg[i] = srcm[i] ? (short)-1 : (short)i;
    __syncthreads();

    for (;;) {
        if (tid == 0) flags[0] = 0;
        __syncthreads();
        bool any = false;
        for (int i = tid; i < NPIX; i += 128) {
            int cur = seg[i];
            if (cur < 0) continue;
            int r = i >> 5, c = i & 31;
            int m = cur;
            if (r > 0) {
                if (c > 0)  { int t = seg[i - 33]; if (t >= 0 && t < m) m = t; }
                { int t = seg[i - 32]; if (t >= 0 && t < m) m = t; }
                if (c < 31) { int t = seg[i - 31]; if (t >= 0 && t < m) m = t; }
            }
            if (c > 0)  { int t = seg[i - 1]; if (t >= 0 && t < m) m = t; }
            if (c < 31) { int t = seg[i + 1]; if (t >= 0 && t < m) m = t; }
            if (r < 31) {
                if (c > 0)  { int t = seg[i + 31]; if (t >= 0 && t < m) m = t; }
                { int t = seg[i + 32]; if (t >= 0 && t < m) m = t; }
                if (c < 31) { int t = seg[i + 33]; if (t >= 0 && t < m) m = t; }
            }
            #pragma unroll
            for (int t2 = 0; t2 < 6; ++t2) {
                int s2 = seg[m];
                if (s2 >= 0 && s2 < m) m = s2; else break;
            }
            if (m < cur) { seg[i] = (short)m; any = true; }
        }
        if (any) flags[0] = 1;
        __syncthreads();
        if (flags[0] == 0) break;
        __syncthreads();
    }

    // compact label ids: seg -> 0 (bg) or 1..K
    for (int i = tid; i < NPIX; i += 128)
        if (seg[i] == (short)i) labId[i] = (short)atomicAdd(&flags[1], 1);
    __syncthreads();
    for (int i = tid; i < NPIX; i += 128) {
        short s2 = seg[i];
        seg[i] = (s2 < 0) ? (short)0 : (short)(labId[s2] + 1);
    }

    // ---- edges (reference order: 992 horizontal then 992 vertical) ----
    for (int e = tid; e < NEDGE; e += 128) {
        int a, b2;
        if (e < NH) { int r = e / 31, c = e - r * 31; a = r * 32 + c; b2 = a + 1; }
        else        { int q = e - NH; int r = q >> 5, c = q & 31; a = r * 32 + c; b2 = a + 32; }
        eab[e]   = (u32)a | ((u32)b2 << 16);
        costs[e] = predL[a] + predL[b2];
        gtcL[e]  = (unsigned char)(tgtL[a] + tgtL[b2]);
    }
    __syncthreads();
    // ======== no block barriers below this line: waves fully decoupled ========

    const int ph = wv;                 // 0 = neg, 1 = pos
    u64*   K     = keys[ph];
    float* Wp    = W[ph];
    short* par_  = par[ph];
    u64*   root_ = root[ph];
    u32*   pool_ = poolS[ph];
    short* H_    = H[ph];

    // keys: (~bits(cost))<<32 | e  => ascending == (cost desc, idx asc) == ref order
    for (int e = lane; e < NEDGE; e += 64) {
        float cv = costs[e];
        int g = gtcL[e];
        if (ph == 0) { if (g > 20) cv = 20.0f; }
        else         { if (g < 10) cv = 0.0f; }
        u32 bits = __float_as_uint(cv);       // costs >= 0: monotone bit pattern
        K[e]  = (((u64)(~bits)) << 32) | (u32)e;
        Wp[e] = 0.0f;
    }
    for (int e = NEDGE + lane; e < NSORT; e += 64) K[e] = ~0ULL;  // tail, never processed

    // union-find init; labeled pixel i owns pool slot i = {seg[i], cnt 1}.
    // labBits: read-only register table — bit s of lane L = "pixel s*64+L is labeled".
    // Invariant (labeled-wins unions): comp has labels <=> seg[root] != 0.
    u32 labBits = 0;
    for (int i = lane; i < NPIX; i += 64) {
        par_[i] = (short)i;
        short s2 = seg[i];
        if (s2) {
            labBits |= 1u << (i >> 6);
            root_[i] = packRoot(1, i, 1, 1);
            pool_[i] = ((u32)(unsigned short)s2 << 16) | 1u;
        } else {
            root_[i] = 0;
        }
        H_[i] = 0;
    }
    if (lane == 0) H_[NPIX] = 0;
    __builtin_amdgcn_wave_barrier();

    // bitonic sort, per-wave (same-wave DS ops are in-order; wave_barrier pins compiler)
    for (int kk = 2; kk <= NSORT; kk <<= 1) {
        for (int j = kk >> 1; j > 0; j >>= 1) {
            for (int i = lane; i < NSORT; i += 64) {
                int ixj = i ^ j;
                if (ixj > i) {
                    u64 x = K[i], y = K[ixj];
                    bool up = ((i & kk) == 0);
                    if ((x > y) == up) { K[i] = y; K[ixj] = x; }
                }
            }
            __builtin_amdgcn_wave_barrier();
        }
    }

    // ---- Kruskal: spec + register-resident labeled-bits; plumbing merges LDS-free ----
    u32 bump = NPIX;               // allocations start in half0
    u32 halfEnd = NPIX + HFS;
    int curHalf = 0;
    const u64 ltm = (1ull << lane) - 1;

    auto do_gc = [&]() {           // ping-pong compaction; live entries <= 1024 < HFS
        u32 tgt = (curHalf == 0) ? (u32)(NPIX + HFS) : (u32)NPIX;
        u32 nb = tgt;
        for (int c = 0; c < 16; ++c) {
            int i0 = c * 64 + lane;
            bool isr = (par_[i0] == (short)i0);
            u64 rbm = __ballot(isr);
            while (rbm) {
                int j = __ffsll(rbm) - 1; rbm &= rbm - 1;
                int r = c * 64 + j;
                u64 R = root_[r];
                int len = R_LEN(R);
                if (len) {
                    int off = R_OFF(R);
                    for (int t = lane; t < len; t += 64) {
                        u32 v2 = pool_[off + t];
                        pool_[nb + t] = v2;
                    }
                    __builtin_amdgcn_wave_barrier();
                    if (lane == 0) root_[r] = packRoot(R_SL(R), (int)nb, len, len);
                    nb += (u32)len;
                }
            }
        }
        bump = nb;
        halfEnd = tgt + HFS;
        curHalf ^= 1;
    };

    int myE = (int)(u32)K[lane];   // group-0 key prefetch
    for (int g2 = 0; g2 < NGRP; ++g2) {
        // spec: resolve true roots for the group's 64 edges (all prior merges done).
        // Path-halving races are benign (any stored value is an ancestor).
        u32 ab = eab[myE];
        int myE_next = (g2 < NGRP - 1) ? (int)(u32)K[(g2 + 1) * 64 + lane] : 0; // prefetch, hidden by drain
        int ra = (int)(ab & 0xFFFF);
        for (;;) { int p = par_[ra]; if (p == ra) break; int q = par_[p]; par_[ra] = (short)q; ra = q; }
        int rb = (int)(ab >> 16);
        for (;;) { int p = par_[rb]; if (p == rb) break; int q = par_[p]; par_[rb] = (short)q; rb = q; }
        bool alive = (ra != rb);
        u32 packed = (u32)myE | ((u32)ra << 11) | ((u32)rb << 21);
        __builtin_amdgcn_wave_barrier();

        for (;;) {
            u64 bal = __ballot(alive);
            if (!bal) break;
            int srcl = __ffsll(bal) - 1;            // lowest lane == sorted order
            u32 v = (u32)rdl((int)packed, srcl);    // v_readlane: ~free vs ds_bpermute
            int me  = (int)(v & 0x7FF);
            int mra = (int)((v >> 11) & 0x3FF);
            int mrb = (int)((v >> 21) & 0x3FF);
            u32 bA = (u32)rdl((int)labBits, mra & 63);
            u32 bB = (u32)rdl((int)labBits, mrb & 63);
            bool labA = (bA >> (mra >> 6)) & 1u;
            bool labB = (bB >> (mrb >> 6)) & 1u;

            int winner, loser;
            if (labA && labB) {
                // weighted merge (~89/phase): the only path touching root_/pool_
                winner = (mra < mrb) ? mra : mrb;
                loser  = (mra < mrb) ? mrb : mra;
                u64 RA = root_[mra], RB = root_[mrb];    // broadcast reads, parallel issue
                int sLa = R_SL(RA), sLb = R_SL(RB);
                int lenA = R_LEN(RA), lenB = R_LEN(RB);
                if (bump + (u32)(lenA + lenB + 8) > halfEnd) {
                    do_gc();
                    RA = root_[mra]; RB = root_[mrb];
                    lenA = R_LEN(RA); lenB = R_LEN(RB);
                }
                int offA = R_OFF(RA), capA = R_CAP(RA);
                int offB = R_OFF(RB), capB = R_CAP(RB);
                int offS, lenS, offL, lenL, capL;
                if (lenA <= lenB) { offS = offA; lenS = lenA; offL = offB; lenL = lenB; capL = capB; }
                else              { offS = offB; lenS = lenB; offL = offA; lenL = lenA; capL = capA; }
                int same;
                int dOff, dLen, dCap;

                if (lenS == 1 && lenL == 1) {
                    u32 xS = pool_[offS];
                    u32 xL = pool_[offL];
                    if ((xS >> 16) == (xL >> 16)) {
                        same = (int)(xS & 0xFFFF) * (int)(xL & 0xFFFF);
                        if (lane == 0) pool_[offL] = xL + (xS & 0xFFFF);
                        dOff = offL; dLen = 1; dCap = capL;
                    } else {
                        same = 0;
                        dOff = (int)bump; dLen = 2; dCap = 8; bump += 8;
                        if (lane == 0) { pool_[dOff] = xL; pool_[dOff + 1] = xS; }
                    }
                } else if (lenS == 1 && lenL <= 64) {
                    u32 xS = pool_[offS];
                    u32 eL = (lane < lenL) ? pool_[offL + lane] : 0u;
                    bool match = (lane < lenL) && ((eL >> 16) == (xS >> 16));
                    u64 mb = __ballot(match);
                    if (mb) {
                        int ml = __ffsll(mb) - 1;
                        u32 eM = (u32)rdl((int)eL, ml);
                        same = (int)(xS & 0xFFFF) * (int)(eM & 0xFFFF);
                        if (match) pool_[offL + lane] = eL + (xS & 0xFFFF);
                        dOff = offL; dLen = lenL; dCap = capL;
                    } else {
                        same = 0;
                        if (lenL < capL) {
                            if (lane == 0) pool_[offL + lenL] = xS;
                            dOff = offL; dLen = lenL + 1; dCap = capL;
                        } else {
                            dOff = (int)bump; dLen = lenL + 1; dCap = (dLen + 4) & ~3; bump += (u32)dCap;
                            if (lane < lenL) pool_[dOff + lane] = eL;
                            if (lane == 0)   pool_[dOff + lenL] = xS;
                        }
                    }
                } else if (lenL <= 64) {
                    // general fast: 2 <= lenS <= lenL <= 64, histogram in H_
                    u32 eS = (lane < lenS) ? pool_[offS + lane] : 0u;
                    u32 eL = (lane < lenL) ? pool_[offL + lane] : 0u;
                    if (lane < lenS) H_[eS >> 16] = (short)(eS & 0xFFFF);
                    __builtin_amdgcn_wave_barrier();
                    int h = (lane < lenL) ? (int)H_[eL >> 16] : 0;
                    same = wredi(h * (int)(eL & 0xFFFF));
                    bool hit = (lane < lenL) && (h != 0);
                    if (hit) H_[eL >> 16] = 0;          // consume matched
                    __builtin_amdgcn_wave_barrier();
                    int h2 = (lane < lenS) ? (int)H_[eS >> 16] : 0;
                    bool un = (h2 != 0);                 // small label not in large
                    u64 ub = __ballot(un);
                    int U = __popcll(ub);
                    if (U == 0 || lenL + U <= capL) { dOff = offL; dCap = capL; }
                    else { dOff = (int)bump; dCap = (lenL + U + 4) & ~3; bump += (u32)dCap; }
                    dLen = lenL + U;
                    if (lane < lenL) pool_[dOff + lane] = eL + (u32)h;
                    if (un) {
                        int pos = __popcll(ub & ltm);
                        pool_[dOff + lenL + pos] = eS;
                        H_[eS >> 16] = 0;
                    }
                } else {
                    // slow generic (lenL > 64): stride loops, always-alloc upper bound
                    dOff = (int)bump;
                    dCap = (lenL + lenS + 4) & ~3; bump += (u32)dCap;
                    for (int j = lane; j < lenS; j += 64) {
                        u32 es = pool_[offS + j];
                        H_[es >> 16] = (short)(es & 0xFFFF);
                    }
                    __builtin_amdgcn_wave_barrier();
                    int sp = 0;
                    for (int j = lane; j < lenL; j += 64) {
                        u32 el = pool_[offL + j];
                        int h = (int)H_[el >> 16];
                        sp += h * (int)(el & 0xFFFF);
                        pool_[dOff + j] = el + (u32)h;
                        if (h) H_[el >> 16] = 0;
                    }
                    same = wredi(sp);
                    __builtin_amdgcn_wave_barrier();
                    int baseU = 0;
                    for (int j0 = 0; j0 < lenS; j0 += 64) {
                        int j = j0 + lane;
                        bool un = false; u32 es = 0;
                        if (j < lenS) { es = pool_[offS + j]; un = (H_[es >> 16] != 0); }
                        u64 ub = __ballot(un);
                        if (un) {
                            int pos = __popcll(ub & ltm);
                            pool_[dOff + lenL + baseU + pos] = es;
                            H_[es >> 16] = 0;
                        }
                        baseU += __popcll(ub);
                    }
                    dLen = lenL + baseU;
                }
                if (lane == 0) {
                    Wp[me] = (float)(ph ? same : (sLa * sLb - same));
                    root_[winner] = packRoot(sLa + sLb, dOff, dLen, dCap);
                }
            } else if (labA) { winner = mra; loser = mrb; }   // labeled wins: root_ untouched
            else if (labB)   { winner = mrb; loser = mra; }
            else             { winner = (mra < mrb) ? mra : mrb; loser = (mra < mrb) ? mrb : mra; }

            if (lane == 0) par_[loser] = (short)winner;       // for next group's spec (off-chain)
            // register-resident relabel: collisions die for free
            if (lane == srcl) alive = false;
            if (ra == loser) ra = winner;
            if (rb == loser) rb = winner;
            if (ra == rb) alive = false;
            packed = (u32)myE | ((u32)ra << 11) | ((u32)rb << 21);
        }
        myE = myE_next;
        __builtin_amdgcn_wave_barrier();
    }

    // ---- epilogue per wave ----
    float s_loc = 0.0f;
    for (int e = lane; e < NEDGE; e += 64) s_loc += Wp[e];
    const float sn = wredf(s_loc);

    const float scale = ph ? lrp_p[0] : lr_p[0];
    float acc = 0.0f;
    for (int e = lane; e < NEDGE; e += 64) {
        float wv2 = Wp[e];
        if (wv2 == 0.0f) continue;
        if (sn > 0.0f) wv2 /= sn;
        int g = gtcL[e];
        bool zero = ph ? (g < 20) : (g >= 10);
        if (zero) continue;
        u32 ab = eab[e];
        float pa = predL[ab & 0xFFFF], pb = predL[ab >> 16];
        float fa2, fb2;
        if (ph == 0) { fa2 = pa * pa; fb2 = pb * pb; }
        else { float qa = 20.0f - pa, qb = 20.0f - pb; fa2 = qa * qa; fb2 = qb * qb; }
        acc += scale * wv2 * (fa2 + fb2);
    }
    acc = wredf(acc);
    if (lane == 0) atomicAdd(out, acc);
}

__global__ void zero_out_kernel(float* o)
{
    if (threadIdx.x == 0 && blockIdx.x == 0) o[0] = 0.0f;
}

extern "C" void kernel_launch(void* const* d_in, const int* in_sizes, int n_in,
                              void* d_out, int out_size, void* d_ws, size_t ws_size,
                              hipStream_t stream)
{
    const float* pred   = (const float*)d_in[0];
    const float* target = (const float*)d_in[1];
    const float* lr     = (const float*)d_in[2];
    const float* lrp    = (const float*)d_in[3];
    float* out = (float*)d_out;

    zero_out_kernel<<<1, 64, 0, stream>>>(out);
    malis_kernel<<<128, 128, 0, stream>>>(pred, target, lr, lrp, out);
}

// Round 6
// 478.107 us; speedup vs baseline: 9.0379x; 1.2971x over previous
//
#include <hip/hip_runtime.h>
#include <cstdint>

#define NPIX  1024
#define NH    992
#define NEDGE 1984
#define NSORT 2048
#define NGRP  31
#define HFS   4300
#define POOLN (NPIX + 2*HFS)   // 9624 u32 entries per phase

typedef unsigned long long u64;
typedef unsigned int u32;

// root_ pack (labeled roots only): sL[0,11) | off[11,25) | len[25,36) | cap[36,47)
static __device__ __forceinline__ u64 packRoot(int sL,int off,int len,int cap){
    return (u64)(u32)(sL & 0x7FF) | ((u64)(u32)(off & 0x3FFF) << 11) |
           ((u64)(u32)(len & 0x7FF) << 25) | ((u64)(u32)(cap & 0x7FF) << 36);
}
#define R_SL(R)  ((int)((R) & 0x7FF))
#define R_OFF(R) ((int)(((R)>>11) & 0x3FFF))
#define R_LEN(R) ((int)(((R)>>25) & 0x7FF))
#define R_CAP(R) ((int)(((R)>>36) & 0x7FF))

static __device__ __forceinline__ int rdl(int v, int l){ return __builtin_amdgcn_readlane(v, l); }

static __device__ __forceinline__ u64 sxor64(u64 v, int m){
    u32 lo = (u32)__shfl_xor((int)(v & 0xFFFFFFFFull), m, 64);
    u32 hi = (u32)__shfl_xor((int)(v >> 32), m, 64);
    return ((u64)hi << 32) | lo;
}

// in-register compare-exchange: x at lower global index
#define CE(x, y, up) { u64 _a=(x), _b=(y); bool _lt=(_a<_b); \
    u64 _mn=_lt?_a:_b, _mx=_lt?_b:_a; (x)=(up)?_mn:_mx; (y)=(up)?_mx:_mn; }
// cross-lane compare-exchange via shfl_xor
#define CEX(x, xm, keepmin) { u64 _p=sxor64((x),(xm)); bool _lt=((x)<_p); \
    u64 _mn=_lt?(x):_p, _mx=_lt?_p:(x); (x)=(keepmin)?_mn:_mx; }

static __device__ __forceinline__ int wredi(int v){
    #pragma unroll
    for (int o = 32; o > 0; o >>= 1) v += __shfl_xor(v, o, 64);
    return v;
}
static __device__ __forceinline__ float wredf(float v){
    #pragma unroll
    for (int o = 32; o > 0; o >>= 1) v += __shfl_xor(v, o, 64);
    return v;
}

__global__ __launch_bounds__(128) void malis_kernel(
    const float* __restrict__ pred,
    const float* __restrict__ target,
    const float* __restrict__ lr_p,
    const float* __restrict__ lrp_p,
    float* __restrict__ out)
{
    const int tid  = threadIdx.x;
    const int lane = tid & 63;
    const int wv   = tid >> 6;        // wave 0: negative pass, wave 1: positive pass
    const int bid  = blockIdx.x;
    const int bb   = bid >> 6;
    const int win  = bid & 63;
    const int wy   = win >> 3, wx = win & 7;
    const int base = bb * 65536 + (wy * 32) * 256 + wx * 32;

    // ---- LDS (~158.9 KB; 1 block/CU) ----
    __shared__ __align__(16) u32 Ks[2][NSORT]; // 16384 sorted edge indices
    __shared__ u64   root[2][NPIX];         // 16384
    __shared__ float W[2][NEDGE];           // 15872
    __shared__ float predL[NPIX];           // 4096
    __shared__ float costs[NEDGE];          // 7936
    __shared__ u32   eab[NEDGE];            // 7936  a | b<<16
    __shared__ u32   poolS[2][POOLN];       // 76992 label-count arrays {lab<<16|cnt}
    __shared__ short seg[NPIX];             // 2048
    __shared__ short par[2][NPIX];          // 4096
    __shared__ short H[2][NPIX + 1];        // 4100 (slow-path histogram only)
    __shared__ unsigned char tgtL[NPIX];    // 1024
    __shared__ unsigned char gtcL[NEDGE];   // 1984
    __shared__ int   flags[2];

    // early scratch overlaid on poolS (dead until UF init)
    unsigned char* mA    = (unsigned char*)poolS;
    unsigned char* mB    = mA + NPIX;
    short*         labId = (short*)(mA + 2 * NPIX);

    // ---- load window ----
    for (int i = tid; i < NPIX; i += 128) {
        int r = i >> 5, c = i & 31;
        float pv = pred[base + r * 256 + c];
        float tv = target[base + r * 256 + c];
        predL[i] = pv;
        tgtL[i]  = (unsigned char)tv;
        mA[i]    = (tv == 0.0f) ? 1 : 0;
    }
    if (tid == 0) flags[1] = 0;
    __syncthreads();

    // ---- dilate 5x (4-neighborhood) ----
    unsigned char* srcm = mA;
    unsigned char* dstm = mB;
    for (int it = 0; it < 5; ++it) {
        for (int i = tid; i < NPIX; i += 128) {
            int r = i >> 5, c = i & 31;
            unsigned char v = srcm[i];
            if (r > 0)  v |= srcm[i - 32];
            if (r < 31) v |= srcm[i + 32];
            if (c > 0)  v |= srcm[i - 1];
            if (c < 31) v |= srcm[i + 1];
            dstm[i] = v;
        }
        __syncthreads();
        unsigned char* t2 = srcm; srcm = dstm; dstm = t2;
    }

    // ---- CCL (8-conn) on fg = !dilated ----
    for (int i = tid; i < NPIX; i += 128)
        seg[i] = srcm[i] ? (short)-1 : (short)i;
    __syncthreads();

    for (;;) {
        if (tid == 0) flags[0] = 0;
        __syncthreads();
        bool any = false;
        for (int i = tid; i < NPIX; i += 128) {
            int cur = seg[i];
            if (cur < 0) continue;
            int r = i >> 5, c = i & 31;
            int m = cur;
            if (r > 0) {
                if (c > 0)  { int t = seg[i - 33]; if (t >= 0 && t < m) m = t; }
                { int t = seg[i - 32]; if (t >= 0 && t < m) m = t; }
                if (c < 31) { int t = seg[i - 31]; if (t >= 0 && t < m) m = t; }
            }
            if (c > 0)  { int t = seg[i - 1]; if (t >= 0 && t < m) m = t; }
            if (c < 31) { int t = seg[i + 1]; if (t >= 0 && t < m) m = t; }
            if (r < 31) {
                if (c > 0)  { int t = seg[i + 31]; if (t >= 0 && t < m) m = t; }
                { int t = seg[i + 32]; if (t >= 0 && t < m) m = t; }
                if (c < 31) { int t = seg[i + 33]; if (t >= 0 && t < m) m = t; }
            }
            #pragma unroll
            for (int t2 = 0; t2 < 6; ++t2) {
                int s2 = seg[m];
                if (s2 >= 0 && s2 < m) m = s2; else break;
            }
            if (m < cur) { seg[i] = (short)m; any = true; }
        }
        if (any) flags[0] = 1;
        __syncthreads();
        if (flags[0] == 0) break;
        __syncthreads();
    }

    // compact label ids: seg -> 0 (bg) or 1..K
    for (int i = tid; i < NPIX; i += 128)
        if (seg[i] == (short)i) labId[i] = (short)atomicAdd(&flags[1], 1);
    __syncthreads();
    for (int i = tid; i < NPIX; i += 128) {
        short s2 = seg[i];
        seg[i] = (s2 < 0) ? (short)0 : (short)(labId[s2] + 1);
    }

    // ---- edges (reference order: 992 horizontal then 992 vertical) ----
    for (int e = tid; e < NEDGE; e += 128) {
        int a, b2;
        if (e < NH) { int r = e / 31, c = e - r * 31; a = r * 32 + c; b2 = a + 1; }
        else        { int q = e - NH; int r = q >> 5, c = q & 31; a = r * 32 + c; b2 = a + 32; }
        eab[e]   = (u32)a | ((u32)b2 << 16);
        costs[e] = predL[a] + predL[b2];
        gtcL[e]  = (unsigned char)(tgtL[a] + tgtL[b2]);
    }
    __syncthreads();
    // ======== no block barriers below this line: waves fully decoupled ========

    const int ph = wv;                 // 0 = neg, 1 = pos
    u32*   Ks_   = Ks[ph];
    float* Wp    = W[ph];
    short* par_  = par[ph];
    u64*   root_ = root[ph];
    u32*   pool_ = poolS[ph];
    short* H_    = H[ph];

    // ---- register-resident bitonic sort of 2048 u64 keys ----
    // layout: global index i = lane*32 + r; key = (~bits(cost))<<32 | e
    // ascending sort == (cost desc, idx asc) == exact reference order
    u64 sk[32];
    #pragma unroll
    for (int r = 0; r < 32; ++r) {
        int e = lane * 32 + r;
        u64 kv = ~0ULL;                       // padding sorts to tail, never read
        if (e < NEDGE) {
            float cv = costs[e];
            int g = gtcL[e];
            if (ph == 0) { if (g > 20) cv = 20.0f; }
            else         { if (g < 10) cv = 0.0f; }
            kv = (((u64)(~__float_as_uint(cv))) << 32) | (u32)e;  // costs >= 0: monotone bits
        }
        sk[r] = kv;
    }
    // phases k=2..32: all in-register (j<32)
    #pragma unroll
    for (int kk2 = 2; kk2 <= 32; kk2 <<= 1) {
        #pragma unroll
        for (int j = kk2 >> 1; j > 0; j >>= 1) {
            #pragma unroll
            for (int r = 0; r < 32; ++r) {
                if ((r & j) == 0) {
                    bool up = (kk2 == 32) ? ((lane & 1) == 0) : ((r & kk2) == 0);
                    CE(sk[r], sk[r | j], up);
                }
            }
        }
    }
    // phases k=64..2048: cross-lane (shfl_xor) then in-register tail
    #pragma unroll
    for (int kk2 = 64; kk2 <= 2048; kk2 <<= 1) {
        const bool up = ((lane & (kk2 >> 5)) == 0);
        #pragma unroll
        for (int j = kk2 >> 1; j >= 32; j >>= 1) {
            const int xm = j >> 5;
            const bool keepmin = (((lane & xm) == 0) == up);
            #pragma unroll
            for (int r = 0; r < 32; ++r) { CEX(sk[r], xm, keepmin); }
        }
        #pragma unroll
        for (int j = 16; j > 0; j >>= 1) {
            #pragma unroll
            for (int r = 0; r < 32; ++r) {
                if ((r & j) == 0) { CE(sk[r], sk[r | j], up); }
            }
        }
    }
    // writeback sorted edge indices (u32) for the spec loop
    #pragma unroll
    for (int r = 0; r < 32; r += 4) {
        uint4 v4;
        v4.x = (u32)sk[r]; v4.y = (u32)sk[r+1]; v4.z = (u32)sk[r+2]; v4.w = (u32)sk[r+3];
        *(uint4*)&Ks_[lane * 32 + r] = v4;
    }

    // ---- union-find init; labeled pixel i owns pool slot i = {seg[i], cnt 1} ----
    // labBits: read-only register table — bit s of lane L = "pixel s*64+L is labeled".
    // Invariant (labeled-wins unions): comp has labels <=> seg[root] != 0.
    u32 labBits = 0;
    for (int i = lane; i < NPIX; i += 64) {
        par_[i] = (short)i;
        short s2 = seg[i];
        if (s2) {
            labBits |= 1u << (i >> 6);
            root_[i] = packRoot(1, i, 1, 1);
            pool_[i] = ((u32)(unsigned short)s2 << 16) | 1u;
        } else {
            root_[i] = 0;
        }
        H_[i] = 0;
    }
    for (int e = lane; e < NEDGE; e += 64) Wp[e] = 0.0f;
    if (lane == 0) H_[NPIX] = 0;
    __builtin_amdgcn_wave_barrier();

    // ---- Kruskal: spec + register labeled-bits; plumbing merges LDS-free ----
    u32 bump = NPIX;               // allocations start in half0
    u32 halfEnd = NPIX + HFS;
    int curHalf = 0;

    auto do_gc = [&]() {           // ping-pong compaction; live entries <= 1024 < HFS
        u32 tgt = (curHalf == 0) ? (u32)(NPIX + HFS) : (u32)NPIX;
        u32 nb = tgt;
        for (int c = 0; c < 16; ++c) {
            int i0 = c * 64 + lane;
            bool isr = (par_[i0] == (short)i0);
            u64 rbm = __ballot(isr);
            while (rbm) {
                int j = __ffsll(rbm) - 1; rbm &= rbm - 1;
                int r = c * 64 + j;
                u64 R = root_[r];
                int len = R_LEN(R);
                if (len) {
                    int off = R_OFF(R);
                    for (int t = lane; t < len; t += 64) {
                        u32 v2 = pool_[off + t];
                        pool_[nb + t] = v2;
                    }
                    __builtin_amdgcn_wave_barrier();
                    if (lane == 0) root_[r] = packRoot(R_SL(R), (int)nb, len, len);
                    nb += (u32)len;
                }
            }
        }
        bump = nb;
        halfEnd = tgt + HFS;
        curHalf ^= 1;
    };

    const u64 ltm = (1ull << lane) - 1;

    for (int g2 = 0; g2 < NGRP; ++g2) {
        // spec: resolve true roots for the group's 64 edges (all prior merges done).
        // Path-halving races are benign (any stored value is an ancestor).
        int myE = (int)Ks_[g2 * 64 + lane];
        u32 ab = eab[myE];
        int ra = (int)(ab & 0xFFFF);
        for (;;) { int p = par_[ra]; if (p == ra) break; int q = par_[p]; par_[ra] = (short)q; ra = q; }
        int rb = (int)(ab >> 16);
        for (;;) { int p = par_[rb]; if (p == rb) break; int q = par_[p]; par_[rb] = (short)q; rb = q; }
        bool alive = (ra != rb);
        u32 packed = (u32)myE | ((u32)ra << 11) | ((u32)rb << 21);
        __builtin_amdgcn_wave_barrier();

        for (;;) {
            u64 bal = __ballot(alive);
            if (!bal) break;
            int srcl = __ffsll(bal) - 1;            // lowest lane == sorted order
            u32 v = (u32)rdl((int)packed, srcl);    // v_readlane broadcast
            int me  = (int)(v & 0x7FF);
            int mra = (int)((v >> 11) & 0x3FF);
            int mrb = (int)((v >> 21) & 0x3FF);
            u32 bA = (u32)rdl((int)labBits, mra & 63);
            u32 bB = (u32)rdl((int)labBits, mrb & 63);
            bool labA = (bA >> (mra >> 6)) & 1u;
            bool labB = (bB >> (mrb >> 6)) & 1u;

            int winner, loser;
            if (labA && labB) {
                // weighted merge (~89/phase): the only path touching root_/pool_
                winner = (mra < mrb) ? mra : mrb;
                loser  = (mra < mrb) ? mrb : mra;
                u64 RA = root_[mra], RB = root_[mrb];    // broadcast reads
                int sLa = R_SL(RA), sLb = R_SL(RB);
                int lenA = R_LEN(RA), lenB = R_LEN(RB);
                if (bump + (u32)(lenA + lenB + 8) > halfEnd) {
                    do_gc();
                    RA = root_[mra]; RB = root_[mrb];
                    lenA = R_LEN(RA); lenB = R_LEN(RB);
                }
                int offA = R_OFF(RA), capA = R_CAP(RA);
                int offB = R_OFF(RB), capB = R_CAP(RB);
                int offS, lenS, offL, lenL, capL;
                if (lenA <= lenB) { offS = offA; lenS = lenA; offL = offB; lenL = lenB; capL = capB; }
                else              { offS = offB; lenS = lenB; offL = offA; lenL = lenA; capL = capA; }
                int same = 0, dOff, dLen, dCap;

                if (lenS + lenL <= 64) {
                    // register path: lists live in lanes; match via readlane+ballot
                    u32 eL = (lane < lenL) ? pool_[offL + lane] : 0u;
                    u32 eS = (lane < lenS) ? pool_[offS + lane] : 0u;
                    dLen = lenL;
                    for (int t = 0; t < lenS; ++t) {
                        u32 xs = (u32)rdl((int)eS, t);
                        bool match = (lane < lenL) && ((eL >> 16) == (xs >> 16));
                        u64 mb = __ballot(match);
                        if (mb) {                               // uniform branch
                            int ml = __ffsll(mb) - 1;
                            same += (int)(xs & 0xFFFF) * ((int)rdl((int)eL, ml) & 0xFFFF);
                            if (match) eL += (xs & 0xFFFF);
                        } else {
                            if (lane == dLen) eL = xs;          // append to free lane
                            dLen++;
                        }
                    }
                    if (dLen <= capL) { dOff = offL; dCap = capL; }     // in place
                    else { dOff = (int)bump; dCap = (dLen + 3) & ~3; bump += (u32)dCap; }
                    if (lane < dLen) pool_[dOff + lane] = eL;
                } else {
                    // slow generic: stride loops + LDS histogram, always-alloc upper bound
                    dOff = (int)bump;
                    dCap = (lenL + lenS + 4) & ~3; bump += (u32)dCap;
                    for (int j = lane; j < lenS; j += 64) {
                        u32 es = pool_[offS + j];
                        H_[es >> 16] = (short)(es & 0xFFFF);
                    }
                    __builtin_amdgcn_wave_barrier();
                    int sp = 0;
                    for (int j = lane; j < lenL; j += 64) {
                        u32 el = pool_[offL + j];
                        int h = (int)H_[el >> 16];
                        sp += h * (int)(el & 0xFFFF);
                        pool_[dOff + j] = el + (u32)h;
                        if (h) H_[el >> 16] = 0;
                    }
                    same = wredi(sp);
                    __builtin_amdgcn_wave_barrier();
                    int baseU = 0;
                    for (int j0 = 0; j0 < lenS; j0 += 64) {
                        int j = j0 + lane;
                        bool un = false; u32 es = 0;
                        if (j < lenS) { es = pool_[offS + j]; un = (H_[es >> 16] != 0); }
                        u64 ub = __ballot(un);
                        if (un) {
                            int pos = __popcll(ub & ltm);
                            pool_[dOff + lenL + baseU + pos] = es;
                            H_[es >> 16] = 0;
                        }
                        baseU += __popcll(ub);
                    }
                    dLen = lenL + baseU;
                }
                if (lane == 0) {
                    Wp[me] = (float)(ph ? same : (sLa * sLb - same));
                    root_[winner] = packRoot(sLa + sLb, dOff, dLen, dCap);
                }
            } else if (labA) { winner = mra; loser = mrb; }   // labeled wins: root_ untouched
            else if (labB)   { winner = mrb; loser = mra; }
            else             { winner = (mra < mrb) ? mra : mrb; loser = (mra < mrb) ? mrb : mra; }

            if (lane == 0) par_[loser] = (short)winner;       // for next group's spec (off-chain)
            // register-resident relabel: collisions die for free
            if (lane == srcl) alive = false;
            if (ra == loser) ra = winner;
            if (rb == loser) rb = winner;
            if (ra == rb) alive = false;
            packed = (u32)myE | ((u32)ra << 11) | ((u32)rb << 21);
        }
        __builtin_amdgcn_wave_barrier();
    }

    // ---- epilogue per wave ----
    float s_loc = 0.0f;
    for (int e = lane; e < NEDGE; e += 64) s_loc += Wp[e];
    const float sn = wredf(s_loc);

    const float scale = ph ? lrp_p[0] : lr_p[0];
    float acc = 0.0f;
    for (int e = lane; e < NEDGE; e += 64) {
        float wv2 = Wp[e];
        if (wv2 == 0.0f) continue;
        if (sn > 0.0f) wv2 /= sn;
        int g = gtcL[e];
        bool zero = ph ? (g < 20) : (g >= 10);
        if (zero) continue;
        u32 ab = eab[e];
        float pa = predL[ab & 0xFFFF], pb = predL[ab >> 16];
        float fa2, fb2;
        if (ph == 0) { fa2 = pa * pa; fb2 = pb * pb; }
        else { float qa = 20.0f - pa, qb = 20.0f - pb; fa2 = qa * qa; fb2 = qb * qb; }
        acc += scale * wv2 * (fa2 + fb2);
    }
    acc = wredf(acc);
    if (lane == 0) atomicAdd(out, acc);
}

__global__ void zero_out_kernel(float* o)
{
    if (threadIdx.x == 0 && blockIdx.x == 0) o[0] = 0.0f;
}

extern "C" void kernel_launch(void* const* d_in, const int* in_sizes, int n_in,
                              void* d_out, int out_size, void* d_ws, size_t ws_size,
                              hipStream_t stream)
{
    const float* pred   = (const float*)d_in[0];
    const float* target = (const float*)d_in[1];
    const float* lr     = (const float*)d_in[2];
    const float* lrp    = (const float*)d_in[3];
    float* out = (float*)d_out;

    zero_out_kernel<<<1, 64, 0, stream>>>(out);
    malis_kernel<<<128, 128, 0, stream>>>(pred, target, lr, lrp, out);
}

// Round 7
// 472.711 us; speedup vs baseline: 9.1410x; 1.0114x over previous
//
#include <hip/hip_runtime.h>
#include <cstdint>

#define NPIX  1024
#define NH    992
#define NEDGE 1984
#define NSORT 2048
#define NGRP  31
#define HFS   4300
#define POOLN (NPIX + 2*HFS)   // 9624 u32 entries per phase

typedef unsigned long long u64;
typedef unsigned int u32;

// root_ pack (labeled live sets only; 0 == dead/unlabeled):
// sL[0,11) | off[11,25) | len[25,36) | cap[36,47)
static __device__ __forceinline__ u64 packRoot(int sL,int off,int len,int cap){
    return (u64)(u32)(sL & 0x7FF) | ((u64)(u32)(off & 0x3FFF) << 11) |
           ((u64)(u32)(len & 0x7FF) << 25) | ((u64)(u32)(cap & 0x7FF) << 36);
}
#define R_SL(R)  ((int)((R) & 0x7FF))
#define R_OFF(R) ((int)(((R)>>11) & 0x3FFF))
#define R_LEN(R) ((int)(((R)>>25) & 0x7FF))
#define R_CAP(R) ((int)(((R)>>36) & 0x7FF))

static __device__ __forceinline__ int rdl(int v, int l){ return __builtin_amdgcn_readlane(v, l); }

static __device__ __forceinline__ u64 sxor64(u64 v, int m){
    u32 lo = (u32)__shfl_xor((int)(v & 0xFFFFFFFFull), m, 64);
    u32 hi = (u32)__shfl_xor((int)(v >> 32), m, 64);
    return ((u64)hi << 32) | lo;
}

// in-register compare-exchange: x at lower global index
#define CE(x, y, up) { u64 _a=(x), _b=(y); bool _lt=(_a<_b); \
    u64 _mn=_lt?_a:_b, _mx=_lt?_b:_a; (x)=(up)?_mn:_mx; (y)=(up)?_mx:_mn; }
// cross-lane compare-exchange via shfl_xor
#define CEX(x, xm, keepmin) { u64 _p=sxor64((x),(xm)); bool _lt=((x)<_p); \
    u64 _mn=_lt?(x):_p, _mx=_lt?_p:(x); (x)=(keepmin)?_mn:_mx; }

static __device__ __forceinline__ int wredi(int v){
    #pragma unroll
    for (int o = 32; o > 0; o >>= 1) v += __shfl_xor(v, o, 64);
    return v;
}
static __device__ __forceinline__ float wredf(float v){
    #pragma unroll
    for (int o = 32; o > 0; o >>= 1) v += __shfl_xor(v, o, 64);
    return v;
}

__global__ __launch_bounds__(128) void malis_kernel(
    const float* __restrict__ pred,
    const float* __restrict__ target,
    const float* __restrict__ lr_p,
    const float* __restrict__ lrp_p,
    float* __restrict__ out)
{
    const int tid  = threadIdx.x;
    const int lane = tid & 63;
    const int wv   = tid >> 6;        // wave 0: negative pass, wave 1: positive pass
    const int bid  = blockIdx.x;
    const int bb   = bid >> 6;
    const int win  = bid & 63;
    const int wy   = win >> 3, wx = win & 7;
    const int base = bb * 65536 + (wy * 32) * 256 + wx * 32;

    // ---- LDS (~155.6 KB; 1 block/CU) ----
    __shared__ __align__(16) u32 Ks[2][NSORT]; // 16384 sorted edge indices
    __shared__ u64   root[2][NPIX];         // 16384 (replay only)
    __shared__ float predL[NPIX];           // 4096
    __shared__ float costs[NEDGE];          // 7936
    __shared__ u32   eab[NEDGE];            // 7936  a | b<<16
    __shared__ u32   poolS[2][POOLN];       // 76992 label-count arrays {lab<<16|cnt}
    __shared__ u32   Q[2][NPIX];            // 8192  weighted-merge records {e,ra,rb}
    __shared__ float Qw[2][NPIX];           // 8192  weights per record
    __shared__ short seg[NPIX];             // 2048
    __shared__ short par[2][NPIX];          // 4096
    __shared__ short H[2][NPIX + 1];        // 4100 (slow-path histogram only)
    __shared__ unsigned char tgtL[NPIX];    // 1024
    __shared__ unsigned char gtcL[NEDGE];   // 1984
    __shared__ int   flags[2];

    // early scratch overlaid on poolS (dead until UF init)
    unsigned char* mA    = (unsigned char*)poolS;
    unsigned char* mB    = mA + NPIX;
    short*         labId = (short*)(mA + 2 * NPIX);

    // ---- load window ----
    for (int i = tid; i < NPIX; i += 128) {
        int r = i >> 5, c = i & 31;
        float pv = pred[base + r * 256 + c];
        float tv = target[base + r * 256 + c];
        predL[i] = pv;
        tgtL[i]  = (unsigned char)tv;
        mA[i]    = (tv == 0.0f) ? 1 : 0;
    }
    if (tid == 0) flags[1] = 0;
    __syncthreads();

    // ---- dilate 5x (4-neighborhood) ----
    unsigned char* srcm = mA;
    unsigned char* dstm = mB;
    for (int it = 0; it < 5; ++it) {
        for (int i = tid; i < NPIX; i += 128) {
            int r = i >> 5, c = i & 31;
            unsigned char v = srcm[i];
            if (r > 0)  v |= srcm[i - 32];
            if (r < 31) v |= srcm[i + 32];
            if (c > 0)  v |= srcm[i - 1];
            if (c < 31) v |= srcm[i + 1];
            dstm[i] = v;
        }
        __syncthreads();
        unsigned char* t2 = srcm; srcm = dstm; dstm = t2;
    }

    // ---- CCL (8-conn) on fg = !dilated ----
    for (int i = tid; i < NPIX; i += 128)
        seg[i] = srcm[i] ? (short)-1 : (short)i;
    __syncthreads();

    for (;;) {
        if (tid == 0) flags[0] = 0;
        __syncthreads();
        bool any = false;
        for (int i = tid; i < NPIX; i += 128) {
            int cur = seg[i];
            if (cur < 0) continue;
            int r = i >> 5, c = i & 31;
            int m = cur;
            if (r > 0) {
                if (c > 0)  { int t = seg[i - 33]; if (t >= 0 && t < m) m = t; }
                { int t = seg[i - 32]; if (t >= 0 && t < m) m = t; }
                if (c < 31) { int t = seg[i - 31]; if (t >= 0 && t < m) m = t; }
            }
            if (c > 0)  { int t = seg[i - 1]; if (t >= 0 && t < m) m = t; }
            if (c < 31) { int t = seg[i + 1]; if (t >= 0 && t < m) m = t; }
            if (r < 31) {
                if (c > 0)  { int t = seg[i + 31]; if (t >= 0 && t < m) m = t; }
                { int t = seg[i + 32]; if (t >= 0 && t < m) m = t; }
                if (c < 31) { int t = seg[i + 33]; if (t >= 0 && t < m) m = t; }
            }
            #pragma unroll
            for (int t2 = 0; t2 < 6; ++t2) {
                int s2 = seg[m];
                if (s2 >= 0 && s2 < m) m = s2; else break;
            }
            if (m < cur) { seg[i] = (short)m; any = true; }
        }
        if (any) flags[0] = 1;
        __syncthreads();
        if (flags[0] == 0) break;
        __syncthreads();
    }

    // compact label ids: seg -> 0 (bg) or 1..K
    for (int i = tid; i < NPIX; i += 128)
        if (seg[i] == (short)i) labId[i] = (short)atomicAdd(&flags[1], 1);
    __syncthreads();
    for (int i = tid; i < NPIX; i += 128) {
        short s2 = seg[i];
        seg[i] = (s2 < 0) ? (short)0 : (short)(labId[s2] + 1);
    }

    // ---- edges (reference order: 992 horizontal then 992 vertical) ----
    for (int e = tid; e < NEDGE; e += 128) {
        int a, b2;
        if (e < NH) { int r = e / 31, c = e - r * 31; a = r * 32 + c; b2 = a + 1; }
        else        { int q = e - NH; int r = q >> 5, c = q & 31; a = r * 32 + c; b2 = a + 32; }
        eab[e]   = (u32)a | ((u32)b2 << 16);
        costs[e] = predL[a] + predL[b2];
        gtcL[e]  = (unsigned char)(tgtL[a] + tgtL[b2]);
    }
    __syncthreads();
    // ======== no block barriers below this line: waves fully decoupled ========

    const int ph = wv;                 // 0 = neg, 1 = pos
    u32*   Ks_   = Ks[ph];
    short* par_  = par[ph];
    u64*   root_ = root[ph];
    u32*   pool_ = poolS[ph];
    short* H_    = H[ph];
    u32*   Q_    = Q[ph];
    float* Qw_   = Qw[ph];

    // ---- register-resident bitonic sort of 2048 u64 keys ----
    // layout: global index i = lane*32 + r; key = (~bits(cost))<<32 | e
    // ascending sort == (cost desc, idx asc) == exact reference order
    u64 sk[32];
    #pragma unroll
    for (int r = 0; r < 32; ++r) {
        int e = lane * 32 + r;
        u64 kv = ~0ULL;                       // padding sorts to tail, never read
        if (e < NEDGE) {
            float cv = costs[e];
            int g = gtcL[e];
            if (ph == 0) { if (g > 20) cv = 20.0f; }
            else         { if (g < 10) cv = 0.0f; }
            kv = (((u64)(~__float_as_uint(cv))) << 32) | (u32)e;  // costs >= 0: monotone bits
        }
        sk[r] = kv;
    }
    #pragma unroll
    for (int kk2 = 2; kk2 <= 32; kk2 <<= 1) {
        #pragma unroll
        for (int j = kk2 >> 1; j > 0; j >>= 1) {
            #pragma unroll
            for (int r = 0; r < 32; ++r) {
                if ((r & j) == 0) {
                    bool up = (kk2 == 32) ? ((lane & 1) == 0) : ((r & kk2) == 0);
                    CE(sk[r], sk[r | j], up);
                }
            }
        }
    }
    #pragma unroll
    for (int kk2 = 64; kk2 <= 2048; kk2 <<= 1) {
        const bool up = ((lane & (kk2 >> 5)) == 0);
        #pragma unroll
        for (int j = kk2 >> 1; j >= 32; j >>= 1) {
            const int xm = j >> 5;
            const bool keepmin = (((lane & xm) == 0) == up);
            #pragma unroll
            for (int r = 0; r < 32; ++r) { CEX(sk[r], xm, keepmin); }
        }
        #pragma unroll
        for (int j = 16; j > 0; j >>= 1) {
            #pragma unroll
            for (int r = 0; r < 32; ++r) {
                if ((r & j) == 0) { CE(sk[r], sk[r | j], up); }
            }
        }
    }
    #pragma unroll
    for (int r = 0; r < 32; r += 4) {
        uint4 v4;
        v4.x = (u32)sk[r]; v4.y = (u32)sk[r+1]; v4.z = (u32)sk[r+2]; v4.w = (u32)sk[r+3];
        *(uint4*)&Ks_[lane * 32 + r] = v4;
    }

    // ---- union-find init; labeled pixel i owns pool slot i = {seg[i], cnt 1} ----
    // Invariant (labeled-wins unions): comp labeled <=> seg[root] != 0, and a
    // root's labeledness NEVER changes during the drain; labeled sets change
    // only at weighted merges (deferred to replay).
    for (int i = lane; i < NPIX; i += 64) {
        par_[i] = (short)i;
        short s2 = seg[i];
        if (s2) {
            root_[i] = packRoot(1, i, 1, 1);
            pool_[i] = ((u32)(unsigned short)s2 << 16) | 1u;
        } else {
            root_[i] = 0;                     // 0 == not a live labeled set
        }
        H_[i] = 0;
    }
    if (lane == 0) H_[NPIX] = 0;
    __builtin_amdgcn_wave_barrier();

    // ---- Kruskal drain: tiny loop, weighted merges recorded for replay ----
    int qn = 0;
    for (int g2 = 0; g2 < NGRP; ++g2) {
        int myE = (int)Ks_[g2 * 64 + lane];
        u32 ab = eab[myE];
        int ra = (int)(ab & 0xFFFF);
        int rb = (int)(ab >> 16);
        // interleaved dual find with path-halving (benign races)
        for (;;) {
            int pa = par_[ra], pb = par_[rb];
            bool fa = (pa != ra), fb = (pb != rb);
            if (!fa && !fb) break;
            int ga = par_[pa], gb = par_[pb];
            if (fa) { par_[ra] = (short)ga; ra = ga; }
            if (fb) { par_[rb] = (short)gb; rb = gb; }
        }
        u32 laA = (seg[ra] != 0) ? 1u : 0u;
        u32 laB = (seg[rb] != 0) ? 1u : 0u;
        bool alive = (ra != rb);
        u32 packed = (u32)ra | ((u32)rb << 10) | (laA << 20) | (laB << 21);
        int myLoser = -1, myWinner = 0;
        __builtin_amdgcn_wave_barrier();

        for (;;) {
            u64 bal = __ballot(alive);
            if (!bal) break;
            int srcl = __ffsll(bal) - 1;            // lowest lane == sorted order
            u32 v = (u32)rdl((int)packed, srcl);
            int mra = (int)(v & 0x3FF);
            int mrb = (int)((v >> 10) & 0x3FF);
            u32 lA = (v >> 20) & 1u, lB = (v >> 21) & 1u;
            int mn = mra < mrb ? mra : mrb;
            int mx = mra < mrb ? mrb : mra;
            int winner = (lA & ~lB) ? mra : ((lB & ~lA) ? mrb : mn);
            int loser  = (lA & ~lB) ? mrb : ((lB & ~lA) ? mra : mx);
            u32 labWin = lA | lB;
            if (lA & lB) {                          // weighted: record, defer sets
                if (lane == srcl) Q_[qn] = (u32)myE | ((u32)ra << 11) | ((u32)rb << 21);
                qn++;
            }
            if (lane == srcl) { myLoser = loser; myWinner = winner; }
            if (ra == loser) { ra = winner; laA = labWin; }
            if (rb == loser) { rb = winner; laB = labWin; }
            alive = alive && (ra != rb);            // srcl + collisions die here
            packed = (u32)ra | ((u32)rb << 10) | (laA << 20) | (laB << 21);
        }
        // batched union writes for next group's finds (each loser unique)
        if (myLoser >= 0) par_[myLoser] = (short)myWinner;
        __builtin_amdgcn_wave_barrier();
    }

    // ---- replay: ~89 weighted merges, sets + weights (exact recorded roots) ----
    u32 bump = NPIX;
    u32 halfEnd = NPIX + HFS;
    int curHalf = 0;
    const u64 ltm = (1ull << lane) - 1;

    auto do_gc = [&]() {           // ping-pong compaction; live entries <= 1024 < HFS
        u32 tgt = (curHalf == 0) ? (u32)(NPIX + HFS) : (u32)NPIX;
        u32 nb = tgt;
        for (int c = 0; c < 16; ++c) {
            int i0 = c * 64 + lane;
            bool live = (root_[i0] != 0);
            u64 rbm = __ballot(live);
            while (rbm) {
                int j = __ffsll(rbm) - 1; rbm &= rbm - 1;
                int r = c * 64 + j;
                u64 R = root_[r];
                int len = R_LEN(R);
                int off = R_OFF(R);
                for (int t = lane; t < len; t += 64) {
                    u32 v2 = pool_[off + t];
                    pool_[nb + t] = v2;
                }
                __builtin_amdgcn_wave_barrier();
                if (lane == 0) root_[r] = packRoot(R_SL(R), (int)nb, len, len);
                nb += (u32)len;
            }
        }
        bump = nb;
        halfEnd = tgt + HFS;
        curHalf ^= 1;
    };

    for (int q = 0; q < qn; ++q) {
        u32 rec = Q_[q];
        int me = (int)(rec & 0x7FF);
        int A  = (int)((rec >> 11) & 0x3FF);
        int B  = (int)((rec >> 21) & 0x3FF);
        int winner = A < B ? A : B;
        int dead   = A < B ? B : A;
        u64 RA = root_[A], RB = root_[B];
        int sLa = R_SL(RA), sLb = R_SL(RB);
        int lenA = R_LEN(RA), lenB = R_LEN(RB);
        if (bump + (u32)(lenA + lenB + 8) > halfEnd) {
            do_gc();
            RA = root_[A]; RB = root_[B];
            lenA = R_LEN(RA); lenB = R_LEN(RB);
        }
        int offA = R_OFF(RA), capA = R_CAP(RA);
        int offB = R_OFF(RB), capB = R_CAP(RB);
        int offS, lenS, offL, lenL, capL;
        if (lenA <= lenB) { offS = offA; lenS = lenA; offL = offB; lenL = lenB; capL = capB; }
        else              { offS = offB; lenS = lenB; offL = offA; lenL = lenA; capL = capA; }
        int same = 0, dOff, dLen, dCap;

        if (lenS + lenL <= 64) {
            // register path: lists live in lanes; match via readlane+ballot
            u32 eL = (lane < lenL) ? pool_[offL + lane] : 0u;
            u32 eS = (lane < lenS) ? pool_[offS + lane] : 0u;
            dLen = lenL;
            for (int t = 0; t < lenS; ++t) {
                u32 xs = (u32)rdl((int)eS, t);
                bool match = (lane < lenL) && ((eL >> 16) == (xs >> 16));
                u64 mb = __ballot(match);
                if (mb) {                               // uniform branch
                    int ml = __ffsll(mb) - 1;
                    same += (int)(xs & 0xFFFF) * ((int)rdl((int)eL, ml) & 0xFFFF);
                    if (match) eL += (xs & 0xFFFF);
                } else {
                    if (lane == dLen) eL = xs;          // append to free lane
                    dLen++;
                }
            }
            if (dLen <= capL) { dOff = offL; dCap = capL; }     // in place
            else { dOff = (int)bump; dCap = (dLen + 3) & ~3; bump += (u32)dCap; }
            if (lane < dLen) pool_[dOff + lane] = eL;
        } else {
            // slow generic: stride loops + LDS histogram, always-alloc upper bound
            dOff = (int)bump;
            dCap = (lenL + lenS + 4) & ~3; bump += (u32)dCap;
            for (int j = lane; j < lenS; j += 64) {
                u32 es = pool_[offS + j];
                H_[es >> 16] = (short)(es & 0xFFFF);
            }
            __builtin_amdgcn_wave_barrier();
            int sp = 0;
            for (int j = lane; j < lenL; j += 64) {
                u32 el = pool_[offL + j];
                int h = (int)H_[el >> 16];
                sp += h * (int)(el & 0xFFFF);
                pool_[dOff + j] = el + (u32)h;
                if (h) H_[el >> 16] = 0;
            }
            same = wredi(sp);
            __builtin_amdgcn_wave_barrier();
            int baseU = 0;
            for (int j0 = 0; j0 < lenS; j0 += 64) {
                int j = j0 + lane;
                bool un = false; u32 es = 0;
                if (j < lenS) { es = pool_[offS + j]; un = (H_[es >> 16] != 0); }
                u64 ub = __ballot(un);
                if (un) {
                    int pos = __popcll(ub & ltm);
                    pool_[dOff + lenL + baseU + pos] = es;
                    H_[es >> 16] = 0;
                }
                baseU += __popcll(ub);
            }
            dLen = lenL + baseU;
        }
        if (lane == 0) {
            Qw_[q] = (float)(ph ? same : (sLa * sLb - same));
            root_[winner] = packRoot(sLa + sLb, dOff, dLen, dCap);
            root_[dead]   = 0;
        }
        __builtin_amdgcn_wave_barrier();
    }

    // ---- epilogue per wave: sums over the qn recorded (merge) edges only ----
    float s_loc = 0.0f;
    for (int q = lane; q < qn; q += 64) s_loc += Qw_[q];
    const float sn = wredf(s_loc);

    const float scale = ph ? lrp_p[0] : lr_p[0];
    float acc = 0.0f;
    for (int q = lane; q < qn; q += 64) {
        float wv2 = Qw_[q];
        if (wv2 == 0.0f) continue;
        if (sn > 0.0f) wv2 /= sn;
        int me = (int)(Q_[q] & 0x7FF);
        int g = gtcL[me];
        bool zero = ph ? (g < 20) : (g >= 10);
        if (zero) continue;
        u32 ab = eab[me];
        float pa = predL[ab & 0xFFFF], pb = predL[ab >> 16];
        float fa2, fb2;
        if (ph == 0) { fa2 = pa * pa; fb2 = pb * pb; }
        else { float qa = 20.0f - pa, qb = 20.0f - pb; fa2 = qa * qa; fb2 = qb * qb; }
        acc += scale * wv2 * (fa2 + fb2);
    }
    acc = wredf(acc);
    if (lane == 0) atomicAdd(out, acc);
}

__global__ void zero_out_kernel(float* o)
{
    if (threadIdx.x == 0 && blockIdx.x == 0) o[0] = 0.0f;
}

extern "C" void kernel_launch(void* const* d_in, const int* in_sizes, int n_in,
                              void* d_out, int out_size, void* d_ws, size_t ws_size,
                              hipStream_t stream)
{
    const float* pred   = (const float*)d_in[0];
    const float* target = (const float*)d_in[1];
    const float* lr     = (const float*)d_in[2];
    const float* lrp    = (const float*)d_in[3];
    float* out = (float*)d_out;

    zero_out_kernel<<<1, 64, 0, stream>>>(out);
    malis_kernel<<<128, 128, 0, stream>>>(pred, target, lr, lrp, out);
}

// Round 8
// 416.808 us; speedup vs baseline: 10.3670x; 1.1341x over previous
//
#include <hip/hip_runtime.h>
#include <cstdint>

#define NPIX  1024
#define NH    992
#define NEDGE 1984
#define NSORT 2048
#define NGRP  31
#define HFS   4300
#define POOLN (NPIX + 2*HFS)   // 9624 u32 entries per phase

typedef unsigned long long u64;
typedef unsigned int u32;

// root_ pack (labeled live sets only; 0 == dead/unlabeled):
// sL[0,11) | off[11,25) | len[25,36) | cap[36,47)
static __device__ __forceinline__ u64 packRoot(int sL,int off,int len,int cap){
    return (u64)(u32)(sL & 0x7FF) | ((u64)(u32)(off & 0x3FFF) << 11) |
           ((u64)(u32)(len & 0x7FF) << 25) | ((u64)(u32)(cap & 0x7FF) << 36);
}
#define R_SL(R)  ((int)((R) & 0x7FF))
#define R_OFF(R) ((int)(((R)>>11) & 0x3FFF))
#define R_LEN(R) ((int)(((R)>>25) & 0x7FF))
#define R_CAP(R) ((int)(((R)>>36) & 0x7FF))

static __device__ __forceinline__ int rdl(int v, int l){ return __builtin_amdgcn_readlane(v, l); }

static __device__ __forceinline__ u64 sxor64(u64 v, int m){
    u32 lo = (u32)__shfl_xor((int)(v & 0xFFFFFFFFull), m, 64);
    u32 hi = (u32)__shfl_xor((int)(v >> 32), m, 64);
    return ((u64)hi << 32) | lo;
}

// in-register compare-exchange: x at lower global index
#define CE(x, y, up) { u64 _a=(x), _b=(y); bool _lt=(_a<_b); \
    u64 _mn=_lt?_a:_b, _mx=_lt?_b:_a; (x)=(up)?_mn:_mx; (y)=(up)?_mx:_mn; }
// cross-lane compare-exchange via shfl_xor
#define CEX(x, xm, keepmin) { u64 _p=sxor64((x),(xm)); bool _lt=((x)<_p); \
    u64 _mn=_lt?(x):_p, _mx=_lt?_p:(x); (x)=(keepmin)?_mn:_mx; }

static __device__ __forceinline__ int wredi(int v){
    #pragma unroll
    for (int o = 32; o > 0; o >>= 1) v += __shfl_xor(v, o, 64);
    return v;
}
static __device__ __forceinline__ float wredf(float v){
    #pragma unroll
    for (int o = 32; o > 0; o >>= 1) v += __shfl_xor(v, o, 64);
    return v;
}

__global__ __launch_bounds__(128) void malis_kernel(
    const float* __restrict__ pred,
    const float* __restrict__ target,
    const float* __restrict__ lr_p,
    const float* __restrict__ lrp_p,
    float* __restrict__ out)
{
    const int tid  = threadIdx.x;
    const int lane = tid & 63;
    const int wv   = tid >> 6;        // wave 0: negative pass, wave 1: positive pass
    const int bid  = blockIdx.x;
    const int bb   = bid >> 6;
    const int win  = bid & 63;
    const int wy   = win >> 3, wx = win & 7;
    const int base = bb * 65536 + (wy * 32) * 256 + wx * 32;

    // ---- LDS (~155.6 KB; 1 block/CU) ----
    __shared__ __align__(16) u32 Ks[2][NSORT]; // 16384 sorted edge indices
    __shared__ u64   root[2][NPIX];         // 16384 (replay only)
    __shared__ float predL[NPIX];           // 4096
    __shared__ float costs[NEDGE];          // 7936
    __shared__ u32   eab[NEDGE];            // 7936  a | b<<16
    __shared__ u32   poolS[2][POOLN];       // 76992 label-count arrays {lab<<16|cnt}
    __shared__ u32   Q[2][NPIX];            // 8192  weighted-merge records {e,ra,rb}
    __shared__ float Qw[2][NPIX];           // 8192  weights per record (claim array during drain)
    __shared__ short seg[NPIX];             // 2048
    __shared__ short par[2][NPIX];          // 4096
    __shared__ short H[2][NPIX + 1];        // 4100 (slow-path histogram only)
    __shared__ unsigned char tgtL[NPIX];    // 1024
    __shared__ unsigned char gtcL[NEDGE];   // 1984
    __shared__ int   flags[2];

    // early scratch overlaid on poolS (dead until UF init)
    unsigned char* mA    = (unsigned char*)poolS;
    unsigned char* mB    = mA + NPIX;
    short*         labId = (short*)(mA + 2 * NPIX);

    // ---- load window ----
    for (int i = tid; i < NPIX; i += 128) {
        int r = i >> 5, c = i & 31;
        float pv = pred[base + r * 256 + c];
        float tv = target[base + r * 256 + c];
        predL[i] = pv;
        tgtL[i]  = (unsigned char)tv;
        mA[i]    = (tv == 0.0f) ? 1 : 0;
    }
    if (tid == 0) flags[1] = 0;
    __syncthreads();

    // ---- dilate 5x (4-neighborhood) ----
    unsigned char* srcm = mA;
    unsigned char* dstm = mB;
    for (int it = 0; it < 5; ++it) {
        for (int i = tid; i < NPIX; i += 128) {
            int r = i >> 5, c = i & 31;
            unsigned char v = srcm[i];
            if (r > 0)  v |= srcm[i - 32];
            if (r < 31) v |= srcm[i + 32];
            if (c > 0)  v |= srcm[i - 1];
            if (c < 31) v |= srcm[i + 1];
            dstm[i] = v;
        }
        __syncthreads();
        unsigned char* t2 = srcm; srcm = dstm; dstm = t2;
    }

    // ---- CCL (8-conn) on fg = !dilated ----
    for (int i = tid; i < NPIX; i += 128)
        seg[i] = srcm[i] ? (short)-1 : (short)i;
    __syncthreads();

    for (;;) {
        if (tid == 0) flags[0] = 0;
        __syncthreads();
        bool any = false;
        for (int i = tid; i < NPIX; i += 128) {
            int cur = seg[i];
            if (cur < 0) continue;
            int r = i >> 5, c = i & 31;
            int m = cur;
            if (r > 0) {
                if (c > 0)  { int t = seg[i - 33]; if (t >= 0 && t < m) m = t; }
                { int t = seg[i - 32]; if (t >= 0 && t < m) m = t; }
                if (c < 31) { int t = seg[i - 31]; if (t >= 0 && t < m) m = t; }
            }
            if (c > 0)  { int t = seg[i - 1]; if (t >= 0 && t < m) m = t; }
            if (c < 31) { int t = seg[i + 1]; if (t >= 0 && t < m) m = t; }
            if (r < 31) {
                if (c > 0)  { int t = seg[i + 31]; if (t >= 0 && t < m) m = t; }
                { int t = seg[i + 32]; if (t >= 0 && t < m) m = t; }
                if (c < 31) { int t = seg[i + 33]; if (t >= 0 && t < m) m = t; }
            }
            #pragma unroll
            for (int t2 = 0; t2 < 6; ++t2) {
                int s2 = seg[m];
                if (s2 >= 0 && s2 < m) m = s2; else break;
            }
            if (m < cur) { seg[i] = (short)m; any = true; }
        }
        if (any) flags[0] = 1;
        __syncthreads();
        if (flags[0] == 0) break;
        __syncthreads();
    }

    // compact label ids: seg -> 0 (bg) or 1..K
    for (int i = tid; i < NPIX; i += 128)
        if (seg[i] == (short)i) labId[i] = (short)atomicAdd(&flags[1], 1);
    __syncthreads();
    for (int i = tid; i < NPIX; i += 128) {
        short s2 = seg[i];
        seg[i] = (s2 < 0) ? (short)0 : (short)(labId[s2] + 1);
    }

    // ---- edges (reference order: 992 horizontal then 992 vertical) ----
    for (int e = tid; e < NEDGE; e += 128) {
        int a, b2;
        if (e < NH) { int r = e / 31, c = e - r * 31; a = r * 32 + c; b2 = a + 1; }
        else        { int q = e - NH; int r = q >> 5, c = q & 31; a = r * 32 + c; b2 = a + 32; }
        eab[e]   = (u32)a | ((u32)b2 << 16);
        costs[e] = predL[a] + predL[b2];
        gtcL[e]  = (unsigned char)(tgtL[a] + tgtL[b2]);
    }
    __syncthreads();
    // ======== no block barriers below this line: waves fully decoupled ========

    const int ph = wv;                 // 0 = neg, 1 = pos
    u32*   Ks_   = Ks[ph];
    short* par_  = par[ph];
    u64*   root_ = root[ph];
    u32*   pool_ = poolS[ph];
    short* H_    = H[ph];
    u32*   Q_    = Q[ph];
    float* Qw_   = Qw[ph];
    u32*   claim_= (u32*)Qw[ph];       // claim array during drain (Qw dead until replay)

    // ---- register-resident bitonic sort of 2048 u64 keys ----
    // layout: global index i = lane*32 + r; key = (~bits(cost))<<32 | e
    // ascending sort == (cost desc, idx asc) == exact reference order
    u64 sk[32];
    #pragma unroll
    for (int r = 0; r < 32; ++r) {
        int e = lane * 32 + r;
        u64 kv = ~0ULL;                       // padding sorts to tail, never read
        if (e < NEDGE) {
            float cv = costs[e];
            int g = gtcL[e];
            if (ph == 0) { if (g > 20) cv = 20.0f; }
            else         { if (g < 10) cv = 0.0f; }
            kv = (((u64)(~__float_as_uint(cv))) << 32) | (u32)e;  // costs >= 0: monotone bits
        }
        sk[r] = kv;
    }
    #pragma unroll
    for (int kk2 = 2; kk2 <= 32; kk2 <<= 1) {
        #pragma unroll
        for (int j = kk2 >> 1; j > 0; j >>= 1) {
            #pragma unroll
            for (int r = 0; r < 32; ++r) {
                if ((r & j) == 0) {
                    bool up = (kk2 == 32) ? ((lane & 1) == 0) : ((r & kk2) == 0);
                    CE(sk[r], sk[r | j], up);
                }
            }
        }
    }
    #pragma unroll
    for (int kk2 = 64; kk2 <= 2048; kk2 <<= 1) {
        const bool up = ((lane & (kk2 >> 5)) == 0);
        #pragma unroll
        for (int j = kk2 >> 1; j >= 32; j >>= 1) {
            const int xm = j >> 5;
            const bool keepmin = (((lane & xm) == 0) == up);
            #pragma unroll
            for (int r = 0; r < 32; ++r) { CEX(sk[r], xm, keepmin); }
        }
        #pragma unroll
        for (int j = 16; j > 0; j >>= 1) {
            #pragma unroll
            for (int r = 0; r < 32; ++r) {
                if ((r & j) == 0) { CE(sk[r], sk[r | j], up); }
            }
        }
    }
    #pragma unroll
    for (int r = 0; r < 32; r += 4) {
        uint4 v4;
        v4.x = (u32)sk[r]; v4.y = (u32)sk[r+1]; v4.z = (u32)sk[r+2]; v4.w = (u32)sk[r+3];
        *(uint4*)&Ks_[lane * 32 + r] = v4;
    }

    // ---- union-find init; labeled pixel i owns pool slot i = {seg[i], cnt 1} ----
    // Invariant (labeled-wins unions): comp labeled <=> seg[root] != 0; labeled
    // sets change only at weighted merges (deferred to replay).
    for (int i = lane; i < NPIX; i += 64) {
        par_[i] = (short)i;
        short s2 = seg[i];
        if (s2) {
            root_[i] = packRoot(1, i, 1, 1);
            pool_[i] = ((u32)(unsigned short)s2 << 16) | 1u;
        } else {
            root_[i] = 0;                     // 0 == not a live labeled set
        }
        H_[i] = 0;
        claim_[i] = ~0u;
    }
    if (lane == 0) H_[NPIX] = 0;
    __builtin_amdgcn_wave_barrier();

    // ---- Kruskal drain: claim-batched parallel merges ----
    // Per round: every alive edge claims its loser (weighted edges claim both
    // roots); claim-winners merge simultaneously (losers exclusive => no par_
    // conflicts; shared winners parallelize hub attachments). Plumbing/mixed
    // merges never change labeled sets, so weights stay exact; weighted edges
    // sharing a root serialize in lane (= sorted) order via the claims.
    int qn = 0;
    const u64 ltm = (1ull << lane) - 1;
    for (int g2 = 0; g2 < NGRP; ++g2) {
        int myE = (int)Ks_[g2 * 64 + lane];
        u32 ab = eab[myE];
        int ra = (int)(ab & 0xFFFF);
        int rb = (int)(ab >> 16);
        // interleaved dual find with path-halving (benign races)
        for (;;) {
            int pa = par_[ra], pb = par_[rb];
            bool fa = (pa != ra), fb = (pb != rb);
            if (!fa && !fb) break;
            int ga = par_[pa], gb = par_[pb];
            if (fa) { par_[ra] = (short)ga; ra = ga; }
            if (fb) { par_[rb] = (short)gb; rb = gb; }
        }
        bool laA = (seg[ra] != 0);
        bool laB = (seg[rb] != 0);
        bool alive = (ra != rb);

        for (;;) {
            if (!__ballot(alive)) break;
            const bool av = alive;
            int mn = ra < rb ? ra : rb;
            int mx = ra < rb ? rb : ra;
            int winner = (laA == laB) ? mn : (laA ? ra : rb);
            int loser  = (laA == laB) ? mx : (laA ? rb : ra);
            bool wgt = laA && laB;
            if (av)        atomicMin(&claim_[loser],  (u32)lane);
            if (av && wgt) atomicMin(&claim_[winner], (u32)lane);
            bool sel = false;
            if (av) {
                u32 cl = claim_[loser];
                u32 cw = wgt ? claim_[winner] : (u32)lane;
                sel = (cl == (u32)lane) && (cw == (u32)lane);
            }
            u64 wm = __ballot(sel && wgt);
            if (sel && wgt) Q_[qn + __popcll(wm & ltm)] =
                (u32)myE | ((u32)mn << 11) | ((u32)mx << 21);
            qn += (int)__popcll(wm);
            if (sel) par_[loser] = (short)winner;
            if (av) { claim_[loser] = ~0u; if (wgt) claim_[winner] = ~0u; }
            if (av) {
                // full find refresh (round chains possible)
                int x = ra;
                for (;;) { int p = par_[x]; if (p == x) break; int q2 = par_[p]; par_[x] = (short)q2; x = q2; }
                int y = rb;
                for (;;) { int p = par_[y]; if (p == y) break; int q2 = par_[p]; par_[y] = (short)q2; y = q2; }
                ra = x; rb = y;
                laA = (seg[ra] != 0);
                laB = (seg[rb] != 0);
                alive = !sel && (ra != rb);
            }
        }
        __builtin_amdgcn_wave_barrier();
    }

    // ---- replay: ~89 weighted merges, sets + weights (exact recorded roots) ----
    u32 bump = NPIX;
    u32 halfEnd = NPIX + HFS;
    int curHalf = 0;

    auto do_gc = [&]() {           // ping-pong compaction; live entries <= 1024 < HFS
        u32 tgt = (curHalf == 0) ? (u32)(NPIX + HFS) : (u32)NPIX;
        u32 nb = tgt;
        for (int c = 0; c < 16; ++c) {
            int i0 = c * 64 + lane;
            bool live = (root_[i0] != 0);
            u64 rbm = __ballot(live);
            while (rbm) {
                int j = __ffsll(rbm) - 1; rbm &= rbm - 1;
                int r = c * 64 + j;
                u64 R = root_[r];
                int len = R_LEN(R);
                int off = R_OFF(R);
                for (int t = lane; t < len; t += 64) {
                    u32 v2 = pool_[off + t];
                    pool_[nb + t] = v2;
                }
                __builtin_amdgcn_wave_barrier();
                if (lane == 0) root_[r] = packRoot(R_SL(R), (int)nb, len, len);
                nb += (u32)len;
            }
        }
        bump = nb;
        halfEnd = tgt + HFS;
        curHalf ^= 1;
    };

    for (int q = 0; q < qn; ++q) {
        u32 rec = Q_[q];
        int me = (int)(rec & 0x7FF);
        int A  = (int)((rec >> 11) & 0x3FF);
        int B  = (int)((rec >> 21) & 0x3FF);
        int winner = A;                 // A = min < B
        int dead   = B;
        u64 RA = root_[A], RB = root_[B];
        int sLa = R_SL(RA), sLb = R_SL(RB);
        int lenA = R_LEN(RA), lenB = R_LEN(RB);
        if (bump + (u32)(lenA + lenB + 8) > halfEnd) {
            do_gc();
            RA = root_[A]; RB = root_[B];
            lenA = R_LEN(RA); lenB = R_LEN(RB);
        }
        int offA = R_OFF(RA), capA = R_CAP(RA);
        int offB = R_OFF(RB), capB = R_CAP(RB);
        int offS, lenS, offL, lenL, capL;
        if (lenA <= lenB) { offS = offA; lenS = lenA; offL = offB; lenL = lenB; capL = capB; }
        else              { offS = offB; lenS = lenB; offL = offA; lenL = lenA; capL = capA; }
        int same = 0, dOff, dLen, dCap;

        if (lenS + lenL <= 64) {
            // register path: lists live in lanes; match via readlane+ballot
            u32 eL = (lane < lenL) ? pool_[offL + lane] : 0u;
            u32 eS = (lane < lenS) ? pool_[offS + lane] : 0u;
            dLen = lenL;
            for (int t = 0; t < lenS; ++t) {
                u32 xs = (u32)rdl((int)eS, t);
                bool match = (lane < lenL) && ((eL >> 16) == (xs >> 16));
                u64 mb = __ballot(match);
                if (mb) {                               // uniform branch
                    int ml = __ffsll(mb) - 1;
                    same += (int)(xs & 0xFFFF) * ((int)rdl((int)eL, ml) & 0xFFFF);
                    if (match) eL += (xs & 0xFFFF);
                } else {
                    if (lane == dLen) eL = xs;          // append to free lane
                    dLen++;
                }
            }
            if (dLen <= capL) { dOff = offL; dCap = capL; }     // in place
            else { dOff = (int)bump; dCap = (dLen + 3) & ~3; bump += (u32)dCap; }
            if (lane < dLen) pool_[dOff + lane] = eL;
        } else {
            // slow generic: stride loops + LDS histogram, always-alloc upper bound
            dOff = (int)bump;
            dCap = (lenL + lenS + 4) & ~3; bump += (u32)dCap;
            for (int j = lane; j < lenS; j += 64) {
                u32 es = pool_[offS + j];
                H_[es >> 16] = (short)(es & 0xFFFF);
            }
            __builtin_amdgcn_wave_barrier();
            int sp = 0;
            for (int j = lane; j < lenL; j += 64) {
                u32 el = pool_[offL + j];
                int h = (int)H_[el >> 16];
                sp += h * (int)(el & 0xFFFF);
                pool_[dOff + j] = el + (u32)h;
                if (h) H_[el >> 16] = 0;
            }
            same = wredi(sp);
            __builtin_amdgcn_wave_barrier();
            int baseU = 0;
            for (int j0 = 0; j0 < lenS; j0 += 64) {
                int j = j0 + lane;
                bool un = false; u32 es = 0;
                if (j < lenS) { es = pool_[offS + j]; un = (H_[es >> 16] != 0); }
                u64 ub = __ballot(un);
                if (un) {
                    int pos = __popcll(ub & ltm);
                    pool_[dOff + lenL + baseU + pos] = es;
                    H_[es >> 16] = 0;
                }
                baseU += __popcll(ub);
            }
            dLen = lenL + baseU;
        }
        if (lane == 0) {
            Qw_[q] = (float)(ph ? same : (sLa * sLb - same));
            root_[winner] = packRoot(sLa + sLb, dOff, dLen, dCap);
            root_[dead]   = 0;
        }
        __builtin_amdgcn_wave_barrier();
    }

    // ---- epilogue per wave: sums over the qn recorded (merge) edges only ----
    float s_loc = 0.0f;
    for (int q = lane; q < qn; q += 64) s_loc += Qw_[q];
    const float sn = wredf(s_loc);

    const float scale = ph ? lrp_p[0] : lr_p[0];
    float acc = 0.0f;
    for (int q = lane; q < qn; q += 64) {
        float wv2 = Qw_[q];
        if (wv2 == 0.0f) continue;
        if (sn > 0.0f) wv2 /= sn;
        int me = (int)(Q_[q] & 0x7FF);
        int g = gtcL[me];
        bool zero = ph ? (g < 20) : (g >= 10);
        if (zero) continue;
        u32 ab = eab[me];
        float pa = predL[ab & 0xFFFF], pb = predL[ab >> 16];
        float fa2, fb2;
        if (ph == 0) { fa2 = pa * pa; fb2 = pb * pb; }
        else { float qa = 20.0f - pa, qb = 20.0f - pb; fa2 = qa * qa; fb2 = qb * qb; }
        acc += scale * wv2 * (fa2 + fb2);
    }
    acc = wredf(acc);
    if (lane == 0) atomicAdd(out, acc);
}

__global__ void zero_out_kernel(float* o)
{
    if (threadIdx.x == 0 && blockIdx.x == 0) o[0] = 0.0f;
}

extern "C" void kernel_launch(void* const* d_in, const int* in_sizes, int n_in,
                              void* d_out, int out_size, void* d_ws, size_t ws_size,
                              hipStream_t stream)
{
    const float* pred   = (const float*)d_in[0];
    const float* target = (const float*)d_in[1];
    const float* lr     = (const float*)d_in[2];
    const float* lrp    = (const float*)d_in[3];
    float* out = (float*)d_out;

    zero_out_kernel<<<1, 64, 0, stream>>>(out);
    malis_kernel<<<128, 128, 0, stream>>>(pred, target, lr, lrp, out);
}